// Round 1
// baseline (1923.873 us; speedup 1.0000x reference)
//
#include <hip/hip_runtime.h>
#include <hip/hip_bf16.h>
#include <math.h>

#define QL 2048
#define HISTN 2048
#define KLEN 4096
#define NH 12
#define NKVH 2
#define HD 128
#define HID 1536
#define NQKV 2048   // 1536 q + 256 k + 256 v
#define QSCALE 0.08838834764831845f  // 1/sqrt(128)

// ---------------- fused QKV projection: qkv = x @ [Wq|Wk|Wv] + [bq|bk|bv] ----
__global__ __launch_bounds__(256) void gemm_qkv(
    const float* __restrict__ x,
    const float* __restrict__ Wq, const float* __restrict__ bq,
    const float* __restrict__ Wk, const float* __restrict__ bk,
    const float* __restrict__ Wv, const float* __restrict__ bv,
    float* __restrict__ out) {
  __shared__ float As[16][68];
  __shared__ float Bs[16][68];
  const int bm0 = blockIdx.y * 64;
  const int bn0 = blockIdx.x * 64;
  const float* W; const float* bias; int ldw, col0;
  if (bn0 < HID)            { W = Wq; bias = bq; ldw = HID; col0 = bn0; }
  else if (bn0 < HID + 256) { W = Wk; bias = bk; ldw = 256; col0 = bn0 - HID; }
  else                      { W = Wv; bias = bv; ldw = 256; col0 = bn0 - HID - 256; }
  const int t = threadIdx.x;
  const int tx = t & 15, ty = t >> 4;
  float acc[4][4] = {};
  for (int k0 = 0; k0 < HID; k0 += 16) {
    for (int i = t; i < 1024; i += 256) {
      int m = i >> 4, kk = i & 15;
      As[kk][m] = x[(size_t)(bm0 + m) * HID + k0 + kk];
    }
    for (int i = t; i < 1024; i += 256) {
      int kk = i >> 6, n = i & 63;
      Bs[kk][n] = W[(size_t)(k0 + kk) * ldw + col0 + n];
    }
    __syncthreads();
#pragma unroll
    for (int kk = 0; kk < 16; ++kk) {
      float4 av  = *(float4*)&As[kk][ty * 4];
      float4 bv4 = *(float4*)&Bs[kk][tx * 4];
      float a[4] = {av.x, av.y, av.z, av.w};
      float b[4] = {bv4.x, bv4.y, bv4.z, bv4.w};
#pragma unroll
      for (int i = 0; i < 4; ++i)
#pragma unroll
        for (int j = 0; j < 4; ++j)
          acc[i][j] = fmaf(a[i], b[j], acc[i][j]);
    }
    __syncthreads();
  }
#pragma unroll
  for (int i = 0; i < 4; ++i) {
    float4 r;
    r.x = acc[i][0] + bias[col0 + tx * 4 + 0];
    r.y = acc[i][1] + bias[col0 + tx * 4 + 1];
    r.z = acc[i][2] + bias[col0 + tx * 4 + 2];
    r.w = acc[i][3] + bias[col0 + tx * 4 + 3];
    *(float4*)&out[(size_t)(bm0 + ty * 4 + i) * NQKV + bn0 + tx * 4] = r;
  }
}

// ---------------- output projection: out = attn @ Wo ------------------------
__global__ __launch_bounds__(256) void gemm_out(
    const float* __restrict__ A, const float* __restrict__ Wo,
    float* __restrict__ out) {
  __shared__ float As[16][68];
  __shared__ float Bs[16][68];
  const int bm0 = blockIdx.y * 64;
  const int bn0 = blockIdx.x * 64;
  const int t = threadIdx.x;
  const int tx = t & 15, ty = t >> 4;
  float acc[4][4] = {};
  for (int k0 = 0; k0 < HID; k0 += 16) {
    for (int i = t; i < 1024; i += 256) {
      int m = i >> 4, kk = i & 15;
      As[kk][m] = A[(size_t)(bm0 + m) * HID + k0 + kk];
    }
    for (int i = t; i < 1024; i += 256) {
      int kk = i >> 6, n = i & 63;
      Bs[kk][n] = Wo[(size_t)(k0 + kk) * HID + bn0 + n];
    }
    __syncthreads();
#pragma unroll
    for (int kk = 0; kk < 16; ++kk) {
      float4 av  = *(float4*)&As[kk][ty * 4];
      float4 bv4 = *(float4*)&Bs[kk][tx * 4];
      float a[4] = {av.x, av.y, av.z, av.w};
      float b[4] = {bv4.x, bv4.y, bv4.z, bv4.w};
#pragma unroll
      for (int i = 0; i < 4; ++i)
#pragma unroll
        for (int j = 0; j < 4; ++j)
          acc[i][j] = fmaf(a[i], b[j], acc[i][j]);
    }
    __syncthreads();
  }
#pragma unroll
  for (int i = 0; i < 4; ++i) {
    float4 r;
    r.x = acc[i][0]; r.y = acc[i][1]; r.z = acc[i][2]; r.w = acc[i][3];
    *(float4*)&out[(size_t)(bm0 + ty * 4 + i) * HID + bn0 + tx * 4] = r;
  }
}

// ---------------- RoPE on q, scatter to [h][q][d], pre-scaled ----------------
__global__ __launch_bounds__(256) void rope_q(
    const float* __restrict__ qkv, const float* __restrict__ cs,
    const float* __restrict__ sn, float* __restrict__ Qb) {
  int idx = blockIdx.x * 256 + threadIdx.x;   // NH*QL*64
  int dp = idx & 63;
  int q  = (idx >> 6) & 2047;
  int h  = idx >> 17;
  const float* base = qkv + (size_t)q * NQKV + h * HD;
  float x1 = base[dp], x2 = base[dp + 64];
  float c = cs[q * 64 + dp], s = sn[q * 64 + dp];
  float* ob = Qb + ((size_t)h * QL + q) * HD;
  ob[dp]      = (x1 * c - x2 * s) * QSCALE;
  ob[dp + 64] = (x1 * s + x2 * c) * QSCALE;
}

// ---------------- K buffer: [kvh][t][d], hist + rope(new) --------------------
__global__ __launch_bounds__(256) void build_k(
    const float* __restrict__ qkv, const float* __restrict__ k_hist,
    const float* __restrict__ cs, const float* __restrict__ sn,
    float* __restrict__ Kb) {
  int idx = blockIdx.x * 256 + threadIdx.x;   // NKVH*KLEN*64
  int dp  = idx & 63;
  int tt  = (idx >> 6) & 4095;
  int kvh = idx >> 18;
  float* ob = Kb + ((size_t)kvh * KLEN + tt) * HD;
  if (tt < HISTN) {
    const float* hb = k_hist + ((size_t)tt * NKVH + kvh) * HD;
    ob[dp] = hb[dp]; ob[dp + 64] = hb[dp + 64];
  } else {
    int q = tt - HISTN;
    const float* base = qkv + (size_t)q * NQKV + HID + kvh * HD;
    float x1 = base[dp], x2 = base[dp + 64];
    float c = cs[q * 64 + dp], s = sn[q * 64 + dp];
    ob[dp]      = x1 * c - x2 * s;
    ob[dp + 64] = x1 * s + x2 * c;
  }
}

// ---------------- V buffer: [kvh][t][d] --------------------------------------
__global__ __launch_bounds__(256) void build_v(
    const float* __restrict__ qkv, const float* __restrict__ v_hist,
    float* __restrict__ Vb) {
  int idx = blockIdx.x * 256 + threadIdx.x;   // NKVH*KLEN*128
  int d   = idx & 127;
  int tt  = (idx >> 7) & 4095;
  int kvh = idx >> 19;
  float v;
  if (tt < HISTN) v = v_hist[((size_t)tt * NKVH + kvh) * HD + d];
  else            v = qkv[(size_t)(tt - HISTN) * NQKV + HID + 256 + kvh * HD + d];
  Vb[((size_t)kvh * KLEN + tt) * HD + d] = v;
}

// ---------------- flash attention (fp32, online softmax) --------------------
__global__ __launch_bounds__(256) void attn_fwd(
    const float* __restrict__ Q, const float* __restrict__ K,
    const float* __restrict__ V, float* __restrict__ Oout) {
  const int h  = blockIdx.y;
  const int q0 = blockIdx.x * 32;
  const int kvh = h / 6;
  const float* Kh = K + (size_t)kvh * KLEN * HD;
  const float* Vh = V + (size_t)kvh * KLEN * HD;
  const float* Qh = Q + ((size_t)h * QL + q0) * HD;

  __shared__ float Qs[32][132];
  __shared__ float Ks[32][132];
  __shared__ float Vs[32][132];
  __shared__ float S[32][33];
  __shared__ float mrow[32], lrow[32], arow[32];

  const int t = threadIdx.x;
  // load Q tile (pre-scaled by 1/sqrt(D))
  for (int i = t; i < 1024; i += 256) {
    int r = i >> 5, c4 = i & 31;
    *(float4*)&Qs[r][c4 * 4] = *(const float4*)&Qh[(size_t)r * HD + c4 * 4];
  }
  if (t < 32) { mrow[t] = -INFINITY; lrow[t] = 0.f; }
  float o[4][4] = {};
  const int qq = t >> 3;   // QK phase: q row 0..31
  const int kq = t & 7;    // QK phase: key lane 0..7 (keys kq+8j)
  const int r0 = t >> 5;   // PV phase: q group 0..7 (rows r0*4+i)
  const int c0 = t & 31;   // PV phase: d group 0..31 (cols c0*4+j)
  const int kend = q0 + 32 + HISTN;
  __syncthreads();

  for (int k0 = 0; k0 < kend; k0 += 32) {
    for (int i = t; i < 1024; i += 256) {
      int r = i >> 5, c4 = i & 31;
      *(float4*)&Ks[r][c4 * 4] = *(const float4*)&Kh[(size_t)(k0 + r) * HD + c4 * 4];
      *(float4*)&Vs[r][c4 * 4] = *(const float4*)&Vh[(size_t)(k0 + r) * HD + c4 * 4];
    }
    __syncthreads();
    // S = Q K^T (scaled), masked
    float s[4] = {0.f, 0.f, 0.f, 0.f};
    for (int c = 0; c < 32; ++c) {
      float4 qv = *(float4*)&Qs[qq][c * 4];
#pragma unroll
      for (int j = 0; j < 4; ++j) {
        float4 kv = *(float4*)&Ks[kq + 8 * j][c * 4];
        s[j] += qv.x * kv.x + qv.y * kv.y + qv.z * kv.z + qv.w * kv.w;
      }
    }
#pragma unroll
    for (int j = 0; j < 4; ++j) {
      int kg = k0 + kq + 8 * j;
      S[qq][kq + 8 * j] = (kg <= q0 + qq + HISTN) ? s[j] : -INFINITY;
    }
    __syncthreads();
    // online softmax per row
    if (t < 32) {
      float m_old = mrow[t], m = m_old;
      for (int k = 0; k < 32; ++k) m = fmaxf(m, S[t][k]);
      float a = __expf(m_old - m);   // first tile: exp(-inf)=0
      float lsum = 0.f;
      for (int k = 0; k < 32; ++k) {
        float p = __expf(S[t][k] - m);
        S[t][k] = p; lsum += p;
      }
      mrow[t] = m; lrow[t] = lrow[t] * a + lsum; arow[t] = a;
    }
    __syncthreads();
    // O = O*alpha + P V
#pragma unroll
    for (int i = 0; i < 4; ++i) {
      float a = arow[r0 * 4 + i];
#pragma unroll
      for (int j = 0; j < 4; ++j) o[i][j] *= a;
    }
    for (int k = 0; k < 32; ++k) {
      float4 vv = *(float4*)&Vs[k][c0 * 4];
#pragma unroll
      for (int i = 0; i < 4; ++i) {
        float p = S[r0 * 4 + i][k];
        o[i][0] = fmaf(p, vv.x, o[i][0]);
        o[i][1] = fmaf(p, vv.y, o[i][1]);
        o[i][2] = fmaf(p, vv.z, o[i][2]);
        o[i][3] = fmaf(p, vv.w, o[i][3]);
      }
    }
    __syncthreads();
  }
#pragma unroll
  for (int i = 0; i < 4; ++i) {
    int q = r0 * 4 + i;
    float inv = 1.f / lrow[q];
    float4 r;
    r.x = o[i][0] * inv; r.y = o[i][1] * inv;
    r.z = o[i][2] * inv; r.w = o[i][3] * inv;
    *(float4*)&Oout[(size_t)(q0 + q) * HID + h * HD + c0 * 4] = r;
  }
}

extern "C" void kernel_launch(void* const* d_in, const int* in_sizes, int n_in,
                              void* d_out, int out_size, void* d_ws, size_t ws_size,
                              hipStream_t stream) {
  (void)in_sizes; (void)n_in; (void)out_size; (void)ws_size;
  const float* x      = (const float*)d_in[0];
  const float* Wq     = (const float*)d_in[1];
  const float* bq     = (const float*)d_in[2];
  const float* Wk     = (const float*)d_in[3];
  const float* bk     = (const float*)d_in[4];
  const float* Wv     = (const float*)d_in[5];
  const float* bv     = (const float*)d_in[6];
  const float* Wo     = (const float*)d_in[7];
  const float* k_hist = (const float*)d_in[8];
  const float* v_hist = (const float*)d_in[9];
  const float* fcos   = (const float*)d_in[10];
  const float* fsin   = (const float*)d_in[11];
  float* out = (float*)d_out;

  float* f    = (float*)d_ws;
  float* qkv  = f;                                   // 2048*2048
  float* Qb   = qkv + (size_t)QL * NQKV;             // 12*2048*128
  float* Kb   = Qb + (size_t)NH * QL * HD;           // 2*4096*128
  float* Vb   = Kb + (size_t)NKVH * KLEN * HD;       // 2*4096*128
  float* attn = Vb + (size_t)NKVH * KLEN * HD;       // 2048*1536

  gemm_qkv<<<dim3(32, 32), 256, 0, stream>>>(x, Wq, bq, Wk, bk, Wv, bv, qkv);
  rope_q <<<6144, 256, 0, stream>>>(qkv, fcos, fsin, Qb);
  build_k<<<2048, 256, 0, stream>>>(qkv, k_hist, fcos, fsin, Kb);
  build_v<<<4096, 256, 0, stream>>>(qkv, v_hist, Vb);
  attn_fwd<<<dim3(64, 12), 256, 0, stream>>>(Qb, Kb, Vb, attn);
  gemm_out<<<dim3(24, 32), 256, 0, stream>>>(attn, Wo, out);
}

// Round 2
// 1115.060 us; speedup vs baseline: 1.7254x; 1.7254x over previous
//
#include <hip/hip_runtime.h>
#include <math.h>

#define QL 2048
#define HISTN 2048
#define KLEN 4096
#define NH 12
#define NKVH 2
#define HD 128
#define HID 1536
#define NQKV 2048   // 1536 q + 256 k + 256 v
#define QSCALE 0.08838834764831845f  // 1/sqrt(128)

typedef unsigned short u16;
typedef short bf16x8 __attribute__((ext_vector_type(8)));
typedef float f32x4 __attribute__((ext_vector_type(4)));

__device__ __forceinline__ u16 f2bf(float f) {
  union { float f; unsigned u; } v; v.f = f;
  unsigned r = v.u + 0x7FFFu + ((v.u >> 16) & 1u);
  return (u16)(r >> 16);
}

// ---------------- fused QKV projection (fp32, unchanged) --------------------
__global__ __launch_bounds__(256) void gemm_qkv(
    const float* __restrict__ x,
    const float* __restrict__ Wq, const float* __restrict__ bq,
    const float* __restrict__ Wk, const float* __restrict__ bk,
    const float* __restrict__ Wv, const float* __restrict__ bv,
    float* __restrict__ out) {
  __shared__ float As[16][68];
  __shared__ float Bs[16][68];
  const int bm0 = blockIdx.y * 64;
  const int bn0 = blockIdx.x * 64;
  const float* W; const float* bias; int ldw, col0;
  if (bn0 < HID)            { W = Wq; bias = bq; ldw = HID; col0 = bn0; }
  else if (bn0 < HID + 256) { W = Wk; bias = bk; ldw = 256; col0 = bn0 - HID; }
  else                      { W = Wv; bias = bv; ldw = 256; col0 = bn0 - HID - 256; }
  const int t = threadIdx.x;
  const int tx = t & 15, ty = t >> 4;
  float acc[4][4] = {};
  for (int k0 = 0; k0 < HID; k0 += 16) {
    for (int i = t; i < 1024; i += 256) {
      int m = i >> 4, kk = i & 15;
      As[kk][m] = x[(size_t)(bm0 + m) * HID + k0 + kk];
    }
    for (int i = t; i < 1024; i += 256) {
      int kk = i >> 6, n = i & 63;
      Bs[kk][n] = W[(size_t)(k0 + kk) * ldw + col0 + n];
    }
    __syncthreads();
#pragma unroll
    for (int kk = 0; kk < 16; ++kk) {
      float4 av  = *(float4*)&As[kk][ty * 4];
      float4 bv4 = *(float4*)&Bs[kk][tx * 4];
      float a[4] = {av.x, av.y, av.z, av.w};
      float b[4] = {bv4.x, bv4.y, bv4.z, bv4.w};
#pragma unroll
      for (int i = 0; i < 4; ++i)
#pragma unroll
        for (int j = 0; j < 4; ++j)
          acc[i][j] = fmaf(a[i], b[j], acc[i][j]);
    }
    __syncthreads();
  }
#pragma unroll
  for (int i = 0; i < 4; ++i) {
    float4 r;
    r.x = acc[i][0] + bias[col0 + tx * 4 + 0];
    r.y = acc[i][1] + bias[col0 + tx * 4 + 1];
    r.z = acc[i][2] + bias[col0 + tx * 4 + 2];
    r.w = acc[i][3] + bias[col0 + tx * 4 + 3];
    *(float4*)&out[(size_t)(bm0 + ty * 4 + i) * NQKV + bn0 + tx * 4] = r;
  }
}

// ---------------- output projection (fp32, unchanged) -----------------------
__global__ __launch_bounds__(256) void gemm_out(
    const float* __restrict__ A, const float* __restrict__ Wo,
    float* __restrict__ out) {
  __shared__ float As[16][68];
  __shared__ float Bs[16][68];
  const int bm0 = blockIdx.y * 64;
  const int bn0 = blockIdx.x * 64;
  const int t = threadIdx.x;
  const int tx = t & 15, ty = t >> 4;
  float acc[4][4] = {};
  for (int k0 = 0; k0 < HID; k0 += 16) {
    for (int i = t; i < 1024; i += 256) {
      int m = i >> 4, kk = i & 15;
      As[kk][m] = A[(size_t)(bm0 + m) * HID + k0 + kk];
    }
    for (int i = t; i < 1024; i += 256) {
      int kk = i >> 6, n = i & 63;
      Bs[kk][n] = Wo[(size_t)(k0 + kk) * HID + bn0 + n];
    }
    __syncthreads();
#pragma unroll
    for (int kk = 0; kk < 16; ++kk) {
      float4 av  = *(float4*)&As[kk][ty * 4];
      float4 bv4 = *(float4*)&Bs[kk][tx * 4];
      float a[4] = {av.x, av.y, av.z, av.w};
      float b[4] = {bv4.x, bv4.y, bv4.z, bv4.w};
#pragma unroll
      for (int i = 0; i < 4; ++i)
#pragma unroll
        for (int j = 0; j < 4; ++j)
          acc[i][j] = fmaf(a[i], b[j], acc[i][j]);
    }
    __syncthreads();
  }
#pragma unroll
  for (int i = 0; i < 4; ++i) {
    float4 r;
    r.x = acc[i][0]; r.y = acc[i][1]; r.z = acc[i][2]; r.w = acc[i][3];
    *(float4*)&out[(size_t)(bm0 + ty * 4 + i) * HID + bn0 + tx * 4] = r;
  }
}

// ---------------- RoPE on q -> bf16 [h][q][d], pre-scaled -------------------
__global__ __launch_bounds__(256) void rope_q(
    const float* __restrict__ qkv, const float* __restrict__ cs,
    const float* __restrict__ sn, u16* __restrict__ Qb) {
  int idx = blockIdx.x * 256 + threadIdx.x;   // NH*QL*64
  int dp = idx & 63;
  int q  = (idx >> 6) & 2047;
  int h  = idx >> 17;
  const float* base = qkv + (size_t)q * NQKV + h * HD;
  float x1 = base[dp], x2 = base[dp + 64];
  float c = cs[q * 64 + dp], s = sn[q * 64 + dp];
  u16* ob = Qb + ((size_t)h * QL + q) * HD;
  ob[dp]      = f2bf((x1 * c - x2 * s) * QSCALE);
  ob[dp + 64] = f2bf((x1 * s + x2 * c) * QSCALE);
}

// ---------------- K buffer -> bf16 [kvh][t][d] -------------------------------
__global__ __launch_bounds__(256) void build_k(
    const float* __restrict__ qkv, const float* __restrict__ k_hist,
    const float* __restrict__ cs, const float* __restrict__ sn,
    u16* __restrict__ Kb) {
  int idx = blockIdx.x * 256 + threadIdx.x;   // NKVH*KLEN*64
  int dp  = idx & 63;
  int tt  = (idx >> 6) & 4095;
  int kvh = idx >> 18;
  u16* ob = Kb + ((size_t)kvh * KLEN + tt) * HD;
  if (tt < HISTN) {
    const float* hb = k_hist + ((size_t)tt * NKVH + kvh) * HD;
    ob[dp] = f2bf(hb[dp]); ob[dp + 64] = f2bf(hb[dp + 64]);
  } else {
    int q = tt - HISTN;
    const float* base = qkv + (size_t)q * NQKV + HID + kvh * HD;
    float x1 = base[dp], x2 = base[dp + 64];
    float c = cs[q * 64 + dp], s = sn[q * 64 + dp];
    ob[dp]      = f2bf(x1 * c - x2 * s);
    ob[dp + 64] = f2bf(x1 * s + x2 * c);
  }
}

// ---------------- V buffer -> bf16 [kvh][t][d] -------------------------------
__global__ __launch_bounds__(256) void build_v(
    const float* __restrict__ qkv, const float* __restrict__ v_hist,
    u16* __restrict__ Vb) {
  int idx = blockIdx.x * 256 + threadIdx.x;   // NKVH*KLEN*128
  int d   = idx & 127;
  int tt  = (idx >> 7) & 4095;
  int kvh = idx >> 19;
  float v;
  if (tt < HISTN) v = v_hist[((size_t)tt * NKVH + kvh) * HD + d];
  else            v = qkv[(size_t)(tt - HISTN) * NQKV + HID + 256 + kvh * HD + d];
  Vb[((size_t)kvh * KLEN + tt) * HD + d] = f2bf(v);
}

// ---------------- flash attention, bf16 MFMA --------------------------------
// Block: 256 thr = 4 waves; wave w owns q rows [q0+16w, q0+16w+16).
// LDS: sK[64][128] bf16 (XOR-swizzled d-blocks), sV[128][64] (V^T, swizzled kk),
//      sP per-wave 16x64 (swizzled). Swizzle: elem block (idx>>3) XOR (row&7).
__global__ __launch_bounds__(256, 4) void attn_mfma(
    const u16* __restrict__ Q, const u16* __restrict__ K,
    const u16* __restrict__ V, float* __restrict__ Oout) {
  __shared__ u16 sK[64 * 128];
  __shared__ u16 sV[128 * 64];
  __shared__ u16 sP[4 * 16 * 64];
  const int h    = blockIdx.y;
  const int q0   = blockIdx.x * 64;
  const int kvh  = h / 6;
  const int t    = threadIdx.x;
  const int lane = t & 63;
  const int w    = t >> 6;
  const int quad = lane >> 4;
  const int l15  = lane & 15;
  const int l7   = lane & 7;

  // stage Q (64x128) into sK, pull per-wave A-frags
  const u16* Qg = Q + ((size_t)h * QL + q0) * HD;
  for (int i = t; i < 2048; i += 256) {
    int row = i >> 5, col4 = i & 31;
    ushort4 q4 = *(const ushort4*)&Qg[row * HD + col4 * 4];
    int pos = row * 128 + ((((col4 >> 1) ^ (row & 7)) << 3) | ((col4 & 1) << 2));
    *(ushort4*)&sK[pos] = q4;
  }
  __syncthreads();
  bf16x8 Qf[4];
  {
    int r = w * 16 + l15;
#pragma unroll
    for (int dc = 0; dc < 4; ++dc)
      Qf[dc] = *(const bf16x8*)&sK[r * 128 + ((((dc << 2) + quad) ^ l7) << 3)];
  }
  __syncthreads();

  f32x4 o[8];
#pragma unroll
  for (int dt = 0; dt < 8; ++dt) o[dt] = (f32x4){0.f, 0.f, 0.f, 0.f};
  float mrow[4] = {-INFINITY, -INFINITY, -INFINITY, -INFINITY};
  float lrow[4] = {0.f, 0.f, 0.f, 0.f};

  const u16* Kh = K + (size_t)kvh * KLEN * HD;
  const u16* Vh = V + (size_t)kvh * KLEN * HD;
  const int kend = q0 + HISTN + 64;
  u16* sPw = sP + w * 1024;

  for (int k0 = 0; k0 < kend; k0 += 64) {
    // ---- stage K tile ----
    const u16* Kg = Kh + (size_t)k0 * HD;
    for (int i = t; i < 2048; i += 256) {
      int row = i >> 5, col4 = i & 31;
      ushort4 k4 = *(const ushort4*)&Kg[row * HD + col4 * 4];
      int pos = row * 128 + ((((col4 >> 1) ^ (row & 7)) << 3) | ((col4 & 1) << 2));
      *(ushort4*)&sK[pos] = k4;
    }
    // ---- stage V tile transposed ----
    const u16* Vg = Vh + (size_t)k0 * HD;
    {
      int kk = t & 63, cb = t >> 6, kb = kk >> 3, kl = kk & 7;
#pragma unroll
      for (int it = 0; it < 8; ++it) {
        int col4 = cb + (it << 2);
        ushort4 v4 = *(const ushort4*)&Vg[kk * HD + col4 * 4];
        int d0 = col4 << 2;
        sV[(d0 + 0) * 64 + (((kb ^ ((d0 + 0) & 7)) << 3) | kl)] = v4.x;
        sV[(d0 + 1) * 64 + (((kb ^ ((d0 + 1) & 7)) << 3) | kl)] = v4.y;
        sV[(d0 + 2) * 64 + (((kb ^ ((d0 + 2) & 7)) << 3) | kl)] = v4.z;
        sV[(d0 + 3) * 64 + (((kb ^ ((d0 + 3) & 7)) << 3) | kl)] = v4.w;
      }
    }
    __syncthreads();

    // ---- S = Q K^T : 4 k-tiles x 4 d-chunks ----
    f32x4 s[4];
#pragma unroll
    for (int kt = 0; kt < 4; ++kt) s[kt] = (f32x4){0.f, 0.f, 0.f, 0.f};
#pragma unroll
    for (int dc = 0; dc < 4; ++dc) {
      int sw = (((dc << 2) + quad) ^ l7) << 3;
#pragma unroll
      for (int kt = 0; kt < 4; ++kt) {
        bf16x8 bK = *(const bf16x8*)&sK[(kt * 16 + l15) * 128 + sw];
        s[kt] = __builtin_amdgcn_mfma_f32_16x16x32_bf16(Qf[dc], bK, s[kt], 0, 0, 0);
      }
    }
    // ---- causal mask (final step only) ----
    if (k0 + 64 >= kend) {
      int qloc = w * 16 + quad * 4;
#pragma unroll
      for (int kt = 0; kt < 4; ++kt) {
        int kkl = kt * 16 + l15;
#pragma unroll
        for (int reg = 0; reg < 4; ++reg)
          if (kkl > qloc + reg) s[kt][reg] = -INFINITY;
      }
    }
    // ---- online softmax (rows = quad*4+reg), write P to LDS ----
    float alpha[4];
#pragma unroll
    for (int reg = 0; reg < 4; ++reg) {
      float v = fmaxf(fmaxf(s[0][reg], s[1][reg]), fmaxf(s[2][reg], s[3][reg]));
      v = fmaxf(v, __shfl_xor(v, 1));
      v = fmaxf(v, __shfl_xor(v, 2));
      v = fmaxf(v, __shfl_xor(v, 4));
      v = fmaxf(v, __shfl_xor(v, 8));
      float mn = fmaxf(mrow[reg], v);
      alpha[reg] = __expf(mrow[reg] - mn);
      mrow[reg] = mn;
      int r = quad * 4 + reg, rx = r & 7, rbase = r * 64;
      float rs = 0.f;
#pragma unroll
      for (int kt = 0; kt < 4; ++kt) {
        float p = __expf(s[kt][reg] - mn);
        rs += p;
        int kkb = (kt << 1) | ((lane >> 3) & 1);
        sPw[rbase + (((kkb ^ rx) << 3) | l7)] = f2bf(p);
      }
      rs += __shfl_xor(rs, 1);
      rs += __shfl_xor(rs, 2);
      rs += __shfl_xor(rs, 4);
      rs += __shfl_xor(rs, 8);
      lrow[reg] = lrow[reg] * alpha[reg] + rs;
    }
    // ---- O = O*alpha + P V ----
#pragma unroll
    for (int dt = 0; dt < 8; ++dt)
#pragma unroll
      for (int reg = 0; reg < 4; ++reg) o[dt][reg] *= alpha[reg];
#pragma unroll
    for (int kc = 0; kc < 2; ++kc) {
      int sw = (((kc << 2) + quad) ^ l7) << 3;
      bf16x8 aP = *(const bf16x8*)&sPw[l15 * 64 + sw];
#pragma unroll
      for (int dt = 0; dt < 8; ++dt) {
        bf16x8 bV = *(const bf16x8*)&sV[(dt * 16 + l15) * 64 + sw];
        o[dt] = __builtin_amdgcn_mfma_f32_16x16x32_bf16(aP, bV, o[dt], 0, 0, 0);
      }
    }
    __syncthreads();
  }
  // ---- epilogue: normalize, store fp32 ----
#pragma unroll
  for (int reg = 0; reg < 4; ++reg) {
    float inv = 1.f / lrow[reg];
    int q = q0 + w * 16 + quad * 4 + reg;
#pragma unroll
    for (int dt = 0; dt < 8; ++dt)
      Oout[(size_t)q * HID + h * HD + dt * 16 + l15] = o[dt][reg] * inv;
  }
}

extern "C" void kernel_launch(void* const* d_in, const int* in_sizes, int n_in,
                              void* d_out, int out_size, void* d_ws, size_t ws_size,
                              hipStream_t stream) {
  (void)in_sizes; (void)n_in; (void)out_size; (void)ws_size;
  const float* x      = (const float*)d_in[0];
  const float* Wq     = (const float*)d_in[1];
  const float* bq     = (const float*)d_in[2];
  const float* Wk     = (const float*)d_in[3];
  const float* bk     = (const float*)d_in[4];
  const float* Wv     = (const float*)d_in[5];
  const float* bv     = (const float*)d_in[6];
  const float* Wo     = (const float*)d_in[7];
  const float* k_hist = (const float*)d_in[8];
  const float* v_hist = (const float*)d_in[9];
  const float* fcos   = (const float*)d_in[10];
  const float* fsin   = (const float*)d_in[11];
  float* out = (float*)d_out;

  float* f    = (float*)d_ws;
  float* qkv  = f;                                   // 2048*2048 f32
  u16*   Qb   = (u16*)(qkv + (size_t)QL * NQKV);     // 12*2048*128 bf16
  u16*   Kb   = Qb + (size_t)NH * QL * HD;           // 2*4096*128 bf16
  u16*   Vb   = Kb + (size_t)NKVH * KLEN * HD;       // 2*4096*128 bf16
  float* attn = (float*)(Vb + (size_t)NKVH * KLEN * HD);
  // align attn to 16B
  attn = (float*)(((uintptr_t)attn + 15) & ~(uintptr_t)15);

  gemm_qkv<<<dim3(32, 32), 256, 0, stream>>>(x, Wq, bq, Wk, bk, Wv, bv, qkv);
  rope_q <<<6144, 256, 0, stream>>>(qkv, fcos, fsin, Qb);
  build_k<<<2048, 256, 0, stream>>>(qkv, k_hist, fcos, fsin, Kb);
  build_v<<<4096, 256, 0, stream>>>(qkv, v_hist, Vb);
  attn_mfma<<<dim3(32, 12), 256, 0, stream>>>(Qb, Kb, Vb, attn);
  gemm_out<<<dim3(24, 32), 256, 0, stream>>>(attn, Wo, out);
}

// Round 3
// 756.234 us; speedup vs baseline: 2.5440x; 1.4745x over previous
//
#include <hip/hip_runtime.h>
#include <math.h>

#define QL 2048
#define HISTN 2048
#define KLEN 4096
#define NH 12
#define NKVH 2
#define HD 128
#define HID 1536
#define NQKV 2048   // 1536 q + 256 k + 256 v
#define QSCALE 0.08838834764831845f  // 1/sqrt(128)

typedef unsigned short u16;
typedef short bf16x8 __attribute__((ext_vector_type(8)));
typedef float f32x4 __attribute__((ext_vector_type(4)));

__device__ __forceinline__ u16 f2bf(float f) {
  union { float f; unsigned u; } v; v.f = f;
  unsigned r = v.u + 0x7FFFu + ((v.u >> 16) & 1u);
  return (u16)(r >> 16);
}
__device__ __forceinline__ float bf2f(u16 h) {
  union { unsigned u; float f; } v; v.u = ((unsigned)h) << 16; return v.f;
}

// ---------------- split fp32 -> bf16 hi + bf16 lo (residual) ----------------
__global__ __launch_bounds__(256) void splitf(const float* __restrict__ in,
    u16* __restrict__ hi, u16* __restrict__ lo, int n4) {
  int i = blockIdx.x * 256 + threadIdx.x;
  if (i >= n4) return;
  float4 v = ((const float4*)in)[i];
  ushort4 h, l;
  h.x = f2bf(v.x); l.x = f2bf(v.x - bf2f(h.x));
  h.y = f2bf(v.y); l.y = f2bf(v.y - bf2f(h.y));
  h.z = f2bf(v.z); l.z = f2bf(v.z - bf2f(h.z));
  h.w = f2bf(v.w); l.w = f2bf(v.w - bf2f(h.w));
  ((ushort4*)hi)[i] = h;
  ((ushort4*)lo)[i] = l;
}

// ------------- transpose + split: W[K][N] -> BtH/BtL [N][K] -----------------
__global__ __launch_bounds__(256) void split_T(const float* __restrict__ W,
    u16* __restrict__ BtH, u16* __restrict__ BtL, int K, int N) {
  __shared__ float T[64][65];
  const int k0 = blockIdx.y * 64, n0 = blockIdx.x * 64;
  const int t = threadIdx.x;
  const int r = t >> 4, c = (t & 15) * 4;
#pragma unroll
  for (int p = 0; p < 4; ++p) {
    float4 v = *(const float4*)&W[(size_t)(k0 + p * 16 + r) * N + n0 + c];
    T[p * 16 + r][c + 0] = v.x; T[p * 16 + r][c + 1] = v.y;
    T[p * 16 + r][c + 2] = v.z; T[p * 16 + r][c + 3] = v.w;
  }
  __syncthreads();
  const int rr = t >> 2, cc0 = (t & 3) * 16;
#pragma unroll
  for (int i4 = 0; i4 < 4; ++i4) {
    float f0 = T[cc0 + i4 * 4 + 0][rr];
    float f1 = T[cc0 + i4 * 4 + 1][rr];
    float f2 = T[cc0 + i4 * 4 + 2][rr];
    float f3 = T[cc0 + i4 * 4 + 3][rr];
    ushort4 h, l;
    h.x = f2bf(f0); l.x = f2bf(f0 - bf2f(h.x));
    h.y = f2bf(f1); l.y = f2bf(f1 - bf2f(h.y));
    h.z = f2bf(f2); l.z = f2bf(f2 - bf2f(h.z));
    h.w = f2bf(f3); l.w = f2bf(f3 - bf2f(h.w));
    size_t off = (size_t)(n0 + rr) * K + k0 + cc0 + i4 * 4;
    *(ushort4*)&BtH[off] = h;
    *(ushort4*)&BtL[off] = l;
  }
}

// ------------- bf16x3 GEMM: C[M][ldc](+c0) = A @ Bt^T (+bias) ---------------
// One wave per block; wave computes 64x64 tile; all frags straight from global.
__global__ __launch_bounds__(64) void gemm3(
    const u16* __restrict__ Ah, const u16* __restrict__ Al,
    const u16* __restrict__ Bh, const u16* __restrict__ Bl,
    const float* __restrict__ bias, float* __restrict__ C,
    int K, int ldc, int c0) {
  const int m0 = blockIdx.y * 64, n0 = blockIdx.x * 64;
  const int lane = threadIdx.x, quad = lane >> 4, l15 = lane & 15;
  f32x4 acc[4][4];
#pragma unroll
  for (int mt = 0; mt < 4; ++mt)
#pragma unroll
    for (int nt = 0; nt < 4; ++nt) acc[mt][nt] = (f32x4){0.f, 0.f, 0.f, 0.f};
  for (int k0 = 0; k0 < K; k0 += 32) {
    bf16x8 ah[4], al[4], bh[4], bl[4];
#pragma unroll
    for (int mt = 0; mt < 4; ++mt) {
      size_t off = (size_t)(m0 + mt * 16 + l15) * K + k0 + quad * 8;
      ah[mt] = *(const bf16x8*)&Ah[off];
      al[mt] = *(const bf16x8*)&Al[off];
    }
#pragma unroll
    for (int nt = 0; nt < 4; ++nt) {
      size_t off = (size_t)(n0 + nt * 16 + l15) * K + k0 + quad * 8;
      bh[nt] = *(const bf16x8*)&Bh[off];
      bl[nt] = *(const bf16x8*)&Bl[off];
    }
#pragma unroll
    for (int mt = 0; mt < 4; ++mt)
#pragma unroll
      for (int nt = 0; nt < 4; ++nt) {
        acc[mt][nt] = __builtin_amdgcn_mfma_f32_16x16x32_bf16(ah[mt], bh[nt], acc[mt][nt], 0, 0, 0);
        acc[mt][nt] = __builtin_amdgcn_mfma_f32_16x16x32_bf16(ah[mt], bl[nt], acc[mt][nt], 0, 0, 0);
        acc[mt][nt] = __builtin_amdgcn_mfma_f32_16x16x32_bf16(al[mt], bh[nt], acc[mt][nt], 0, 0, 0);
      }
  }
#pragma unroll
  for (int nt = 0; nt < 4; ++nt) {
    float bv = bias ? bias[n0 + nt * 16 + l15] : 0.f;
#pragma unroll
    for (int mt = 0; mt < 4; ++mt)
#pragma unroll
      for (int reg = 0; reg < 4; ++reg) {
        int row = m0 + mt * 16 + quad * 4 + reg;
        C[(size_t)row * ldc + c0 + n0 + nt * 16 + l15] = acc[mt][nt][reg] + bv;
      }
  }
}

// ---------------- RoPE on q -> bf16 [h][q][d], pre-scaled -------------------
__global__ __launch_bounds__(256) void rope_q(
    const float* __restrict__ qkv, const float* __restrict__ cs,
    const float* __restrict__ sn, u16* __restrict__ Qb) {
  int idx = blockIdx.x * 256 + threadIdx.x;   // NH*QL*64
  int dp = idx & 63;
  int q  = (idx >> 6) & 2047;
  int h  = idx >> 17;
  const float* base = qkv + (size_t)q * NQKV + h * HD;
  float x1 = base[dp], x2 = base[dp + 64];
  float c = cs[q * 64 + dp], s = sn[q * 64 + dp];
  u16* ob = Qb + ((size_t)h * QL + q) * HD;
  ob[dp]      = f2bf((x1 * c - x2 * s) * QSCALE);
  ob[dp + 64] = f2bf((x1 * s + x2 * c) * QSCALE);
}

// ---------------- K buffer -> bf16 [kvh][t][d] -------------------------------
__global__ __launch_bounds__(256) void build_k(
    const float* __restrict__ qkv, const float* __restrict__ k_hist,
    const float* __restrict__ cs, const float* __restrict__ sn,
    u16* __restrict__ Kb) {
  int idx = blockIdx.x * 256 + threadIdx.x;   // NKVH*KLEN*64
  int dp  = idx & 63;
  int tt  = (idx >> 6) & 4095;
  int kvh = idx >> 18;
  u16* ob = Kb + ((size_t)kvh * KLEN + tt) * HD;
  if (tt < HISTN) {
    const float* hb = k_hist + ((size_t)tt * NKVH + kvh) * HD;
    ob[dp] = f2bf(hb[dp]); ob[dp + 64] = f2bf(hb[dp + 64]);
  } else {
    int q = tt - HISTN;
    const float* base = qkv + (size_t)q * NQKV + HID + kvh * HD;
    float x1 = base[dp], x2 = base[dp + 64];
    float c = cs[q * 64 + dp], s = sn[q * 64 + dp];
    ob[dp]      = f2bf(x1 * c - x2 * s);
    ob[dp + 64] = f2bf(x1 * s + x2 * c);
  }
}

// ---------------- V^T buffer -> bf16 [kvh][d][t] -----------------------------
__global__ __launch_bounds__(256) void build_vt(
    const float* __restrict__ qkv, const float* __restrict__ v_hist,
    u16* __restrict__ Vt) {
  int idx = blockIdx.x * 256 + threadIdx.x;   // NKVH*HD*1024
  int t4  = idx & 1023;
  int d   = (idx >> 10) & 127;
  int kvh = idx >> 17;
  int tt = t4 * 4;
  ushort4 o;
  float f[4];
#pragma unroll
  for (int j = 0; j < 4; ++j) {
    int tj = tt + j;
    f[j] = (tj < HISTN)
         ? v_hist[((size_t)tj * NKVH + kvh) * HD + d]
         : qkv[(size_t)(tj - HISTN) * NQKV + HID + 256 + kvh * HD + d];
  }
  o.x = f2bf(f[0]); o.y = f2bf(f[1]); o.z = f2bf(f[2]); o.w = f2bf(f[3]);
  *(ushort4*)&Vt[((size_t)kvh * HD + d) * KLEN + tt] = o;
}

// -------- flash attention: 16 q-rows/block, 4 waves split the key range -----
// No barriers in the K-loop; frags direct from global (L2-resident K/Vt);
// per-wave LDS patch only for the P C-layout -> A-layout transpose.
__global__ __launch_bounds__(256) void attn_splitk(
    const u16* __restrict__ Q, const u16* __restrict__ K,
    const u16* __restrict__ Vt, u16* __restrict__ OH, u16* __restrict__ OL) {
  __shared__ u16 sP[4][16 * 72];        // pad 72: 2-way bank = free
  __shared__ float cO[2][16][132];      // combine buffers, pad 132
  __shared__ float cM[2][16], cL[2][16];
  const int h = blockIdx.y, q0 = blockIdx.x * 16, kvh = h / 6;
  const int t = threadIdx.x, lane = t & 63, w = t >> 6;
  const int quad = lane >> 4, l15 = lane & 15;

  const u16* Qg = Q + ((size_t)h * QL + q0) * HD;
  bf16x8 Qf[4];
#pragma unroll
  for (int dc = 0; dc < 4; ++dc)
    Qf[dc] = *(const bf16x8*)&Qg[l15 * HD + dc * 32 + quad * 8];

  const int nsteps = (q0 + 16 + HISTN + 63) >> 6;
  const int bas = nsteps >> 2, rem = nsteps & 3;
  const int cnt = bas + (w < rem ? 1 : 0);
  const int s0  = w * bas + (w < rem ? w : rem);

  f32x4 o[8];
#pragma unroll
  for (int dt = 0; dt < 8; ++dt) o[dt] = (f32x4){0.f, 0.f, 0.f, 0.f};
  float mrow[4] = {-INFINITY, -INFINITY, -INFINITY, -INFINITY};
  float lrow[4] = {0.f, 0.f, 0.f, 0.f};

  const u16* Kh = K + (size_t)kvh * KLEN * HD;
  const u16* Vh = Vt + (size_t)kvh * HD * KLEN;
  u16* sPw = sP[w];

  for (int s = s0; s < s0 + cnt; ++s) {
    const int k0 = s << 6;
    f32x4 sc[4];
#pragma unroll
    for (int kt = 0; kt < 4; ++kt) sc[kt] = (f32x4){0.f, 0.f, 0.f, 0.f};
#pragma unroll
    for (int dc = 0; dc < 4; ++dc) {
#pragma unroll
      for (int kt = 0; kt < 4; ++kt) {
        bf16x8 bK = *(const bf16x8*)&Kh[(size_t)(k0 + kt * 16 + l15) * HD + dc * 32 + quad * 8];
        sc[kt] = __builtin_amdgcn_mfma_f32_16x16x32_bf16(Qf[dc], bK, sc[kt], 0, 0, 0);
      }
    }
    if (k0 + 63 > q0 + HISTN) {   // boundary not 64-aligned: may span 2 steps
#pragma unroll
      for (int kt = 0; kt < 4; ++kt) {
        int kg = k0 + kt * 16 + l15;
#pragma unroll
        for (int reg = 0; reg < 4; ++reg)
          if (kg > q0 + quad * 4 + reg + HISTN) sc[kt][reg] = -INFINITY;
      }
    }
    float alpha[4];
#pragma unroll
    for (int reg = 0; reg < 4; ++reg) {
      float v = fmaxf(fmaxf(sc[0][reg], sc[1][reg]), fmaxf(sc[2][reg], sc[3][reg]));
      v = fmaxf(v, __shfl_xor(v, 1));
      v = fmaxf(v, __shfl_xor(v, 2));
      v = fmaxf(v, __shfl_xor(v, 4));
      v = fmaxf(v, __shfl_xor(v, 8));
      float mn = fmaxf(mrow[reg], v);
      alpha[reg] = __expf(mrow[reg] - mn);
      mrow[reg] = mn;
      int row = quad * 4 + reg;
      float rs = 0.f;
#pragma unroll
      for (int kt = 0; kt < 4; ++kt) {
        float p = __expf(sc[kt][reg] - mn);
        rs += p;
        sPw[row * 72 + kt * 16 + l15] = f2bf(p);
      }
      rs += __shfl_xor(rs, 1);
      rs += __shfl_xor(rs, 2);
      rs += __shfl_xor(rs, 4);
      rs += __shfl_xor(rs, 8);
      lrow[reg] = lrow[reg] * alpha[reg] + rs;
    }
#pragma unroll
    for (int dt = 0; dt < 8; ++dt)
#pragma unroll
      for (int reg = 0; reg < 4; ++reg) o[dt][reg] *= alpha[reg];
#pragma unroll
    for (int kc = 0; kc < 2; ++kc) {
      bf16x8 aP = *(const bf16x8*)&sPw[l15 * 72 + kc * 32 + quad * 8];
#pragma unroll
      for (int dt = 0; dt < 8; ++dt) {
        bf16x8 bV = *(const bf16x8*)&Vh[(size_t)(dt * 16 + l15) * KLEN + k0 + kc * 32 + quad * 8];
        o[dt] = __builtin_amdgcn_mfma_f32_16x16x32_bf16(aP, bV, o[dt], 0, 0, 0);
      }
    }
  }

  // ---- merge tree: (1,3) -> LDS; (0,2) merge; 2 -> LDS; 0 merges + stores ----
  if (w & 1) {
    int buf = w >> 1;
#pragma unroll
    for (int reg = 0; reg < 4; ++reg) {
      int row = quad * 4 + reg;
      if (l15 == 0) { cM[buf][row] = mrow[reg]; cL[buf][row] = lrow[reg]; }
#pragma unroll
      for (int dt = 0; dt < 8; ++dt) cO[buf][row][dt * 16 + l15] = o[dt][reg];
    }
  }
  __syncthreads();
  if (!(w & 1)) {
    int buf = w >> 1;
#pragma unroll
    for (int reg = 0; reg < 4; ++reg) {
      int row = quad * 4 + reg;
      float m2 = cM[buf][row], l2 = cL[buf][row];
      float mn = fmaxf(mrow[reg], m2);
      float a1 = __expf(mrow[reg] - mn), a2 = __expf(m2 - mn);
      lrow[reg] = lrow[reg] * a1 + l2 * a2;
      mrow[reg] = mn;
#pragma unroll
      for (int dt = 0; dt < 8; ++dt)
        o[dt][reg] = o[dt][reg] * a1 + cO[buf][row][dt * 16 + l15] * a2;
    }
  }
  __syncthreads();
  if (w == 2) {
#pragma unroll
    for (int reg = 0; reg < 4; ++reg) {
      int row = quad * 4 + reg;
      if (l15 == 0) { cM[1][row] = mrow[reg]; cL[1][row] = lrow[reg]; }
#pragma unroll
      for (int dt = 0; dt < 8; ++dt) cO[1][row][dt * 16 + l15] = o[dt][reg];
    }
  }
  __syncthreads();
  if (w == 0) {
#pragma unroll
    for (int reg = 0; reg < 4; ++reg) {
      int row = quad * 4 + reg;
      float m2 = cM[1][row], l2 = cL[1][row];
      float mn = fmaxf(mrow[reg], m2);
      float a1 = __expf(mrow[reg] - mn), a2 = __expf(m2 - mn);
      float li = lrow[reg] * a1 + l2 * a2;
      float inv = 1.f / li;
#pragma unroll
      for (int dt = 0; dt < 8; ++dt) {
        float val = (o[dt][reg] * a1 + cO[1][row][dt * 16 + l15] * a2) * inv;
        u16 hv = f2bf(val);
        size_t oi = (size_t)(q0 + row) * HID + h * HD + dt * 16 + l15;
        OH[oi] = hv;
        OL[oi] = f2bf(val - bf2f(hv));
      }
    }
  }
}

extern "C" void kernel_launch(void* const* d_in, const int* in_sizes, int n_in,
                              void* d_out, int out_size, void* d_ws, size_t ws_size,
                              hipStream_t stream) {
  (void)in_sizes; (void)n_in; (void)out_size; (void)ws_size;
  const float* x      = (const float*)d_in[0];
  const float* Wq     = (const float*)d_in[1];
  const float* bq     = (const float*)d_in[2];
  const float* Wk     = (const float*)d_in[3];
  const float* bk     = (const float*)d_in[4];
  const float* Wv     = (const float*)d_in[5];
  const float* bv     = (const float*)d_in[6];
  const float* Wo     = (const float*)d_in[7];
  const float* k_hist = (const float*)d_in[8];
  const float* v_hist = (const float*)d_in[9];
  const float* fcos   = (const float*)d_in[10];
  const float* fsin   = (const float*)d_in[11];
  float* out = (float*)d_out;

  char* p = (char*)d_ws;
  float* qkv  = (float*)p;                 p += (size_t)QL * NQKV * 4;        // 16.78 MB
  u16*   Qb   = (u16*)p;                   p += (size_t)NH * QL * HD * 2;     // 6.29
  u16*   Kb   = (u16*)p;                   p += (size_t)NKVH * KLEN * HD * 2; // 2.10
  u16*   Vtb  = (u16*)p;                   p += (size_t)NKVH * HD * KLEN * 2; // 2.10
  u16*   xh   = (u16*)p;                   p += (size_t)QL * HID * 2;         // 6.29 (reused: attnH)
  u16*   xl   = (u16*)p;                   p += (size_t)QL * HID * 2;         // 6.29 (reused: attnL)
  u16*   WqtH = (u16*)p;                   p += (size_t)HID * HID * 2;        // 4.72 (reused: WotH)
  u16*   WqtL = (u16*)p;                   p += (size_t)HID * HID * 2;        // 4.72 (reused: WotL)
  u16*   WktH = (u16*)p;                   p += (size_t)256 * HID * 2;
  u16*   WktL = (u16*)p;                   p += (size_t)256 * HID * 2;
  u16*   WvtH = (u16*)p;                   p += (size_t)256 * HID * 2;
  u16*   WvtL = (u16*)p;                   p += (size_t)256 * HID * 2;        // total ~50 MB
  u16* attnH = xh;  u16* attnL = xl;       // x dead after qkv gemms
  u16* WotH = WqtH; u16* WotL = WqtL;      // Wqt dead after gemm3-q

  splitf <<<3072, 256, 0, stream>>>(x, xh, xl, (int)((size_t)QL * HID / 4));
  split_T<<<dim3(24, 24), 256, 0, stream>>>(Wq, WqtH, WqtL, HID, HID);
  split_T<<<dim3(4, 24), 256, 0, stream>>>(Wk, WktH, WktL, HID, 256);
  split_T<<<dim3(4, 24), 256, 0, stream>>>(Wv, WvtH, WvtL, HID, 256);

  gemm3<<<dim3(24, 32), 64, 0, stream>>>(xh, xl, WqtH, WqtL, bq, qkv, HID, NQKV, 0);
  gemm3<<<dim3(4, 32), 64, 0, stream>>>(xh, xl, WktH, WktL, bk, qkv, HID, NQKV, HID);
  gemm3<<<dim3(4, 32), 64, 0, stream>>>(xh, xl, WvtH, WvtL, bv, qkv, HID, NQKV, HID + 256);

  split_T<<<dim3(24, 24), 256, 0, stream>>>(Wo, WotH, WotL, HID, HID);  // after gemm3-q

  rope_q  <<<6144, 256, 0, stream>>>(qkv, fcos, fsin, Qb);
  build_k <<<2048, 256, 0, stream>>>(qkv, k_hist, fcos, fsin, Kb);
  build_vt<<<1024, 256, 0, stream>>>(qkv, v_hist, Vtb);

  attn_splitk<<<dim3(128, 12), 256, 0, stream>>>(Qb, Kb, Vtb, attnH, attnL);

  gemm3<<<dim3(24, 32), 64, 0, stream>>>(attnH, attnL, WotH, WotL, nullptr, out, HID, HID, 0);
}

// Round 4
// 531.828 us; speedup vs baseline: 3.6175x; 1.4220x over previous
//
#include <hip/hip_runtime.h>
#include <math.h>

#define QL 2048
#define HISTN 2048
#define KLEN 4096
#define NH 12
#define NKVH 2
#define HD 128
#define HID 1536
#define NQKV 2048   // 1536 q + 256 k + 256 v
#define VTROWS 144  // 128 d + 1 ones + 15 zeros
#define QSCALE 0.08838834764831845f  // 1/sqrt(128)

typedef unsigned short u16;
typedef short bf16x8 __attribute__((ext_vector_type(8)));
typedef float f32x4 __attribute__((ext_vector_type(4)));

__device__ __forceinline__ u16 f2bf(float f) {
  union { float f; unsigned u; } v; v.f = f;
  unsigned r = v.u + 0x7FFFu + ((v.u >> 16) & 1u);
  return (u16)(r >> 16);
}
__device__ __forceinline__ float bf2f(u16 h) {
  union { unsigned u; float f; } v; v.u = ((unsigned)h) << 16; return v.f;
}

// ---------------- split fp32 -> bf16 hi + bf16 lo (residual) ----------------
__global__ __launch_bounds__(256) void splitf(const float* __restrict__ in,
    u16* __restrict__ hi, u16* __restrict__ lo, int n4) {
  int i = blockIdx.x * 256 + threadIdx.x;
  if (i >= n4) return;
  float4 v = ((const float4*)in)[i];
  ushort4 h, l;
  h.x = f2bf(v.x); l.x = f2bf(v.x - bf2f(h.x));
  h.y = f2bf(v.y); l.y = f2bf(v.y - bf2f(h.y));
  h.z = f2bf(v.z); l.z = f2bf(v.z - bf2f(h.z));
  h.w = f2bf(v.w); l.w = f2bf(v.w - bf2f(h.w));
  ((ushort4*)hi)[i] = h;
  ((ushort4*)lo)[i] = l;
}

// ------------- transpose + split: W[K][N] -> BtH/BtL [N][K] -----------------
__global__ __launch_bounds__(256) void split_T(const float* __restrict__ W,
    u16* __restrict__ BtH, u16* __restrict__ BtL, int K, int N) {
  __shared__ float T[64][65];
  const int k0 = blockIdx.y * 64, n0 = blockIdx.x * 64;
  const int t = threadIdx.x;
  const int r = t >> 4, c = (t & 15) * 4;
#pragma unroll
  for (int p = 0; p < 4; ++p) {
    float4 v = *(const float4*)&W[(size_t)(k0 + p * 16 + r) * N + n0 + c];
    T[p * 16 + r][c + 0] = v.x; T[p * 16 + r][c + 1] = v.y;
    T[p * 16 + r][c + 2] = v.z; T[p * 16 + r][c + 3] = v.w;
  }
  __syncthreads();
  const int rr = t >> 2, cc0 = (t & 3) * 16;
#pragma unroll
  for (int i4 = 0; i4 < 4; ++i4) {
    float f0 = T[cc0 + i4 * 4 + 0][rr];
    float f1 = T[cc0 + i4 * 4 + 1][rr];
    float f2 = T[cc0 + i4 * 4 + 2][rr];
    float f3 = T[cc0 + i4 * 4 + 3][rr];
    ushort4 h, l;
    h.x = f2bf(f0); l.x = f2bf(f0 - bf2f(h.x));
    h.y = f2bf(f1); l.y = f2bf(f1 - bf2f(h.y));
    h.z = f2bf(f2); l.z = f2bf(f2 - bf2f(h.z));
    h.w = f2bf(f3); l.w = f2bf(f3 - bf2f(h.w));
    size_t off = (size_t)(n0 + rr) * K + k0 + cc0 + i4 * 4;
    *(ushort4*)&BtH[off] = h;
    *(ushort4*)&BtL[off] = l;
  }
}

// ---------------- bias concat [bq|bk|bv] ------------------------------------
__global__ __launch_bounds__(256) void bcat_k(const float* __restrict__ bq,
    const float* __restrict__ bk, const float* __restrict__ bv,
    float* __restrict__ o) {
  int i = blockIdx.x * 256 + threadIdx.x;
  if (i >= NQKV) return;
  o[i] = (i < HID) ? bq[i] : (i < HID + 256 ? bk[i - HID] : bv[i - HID - 256]);
}

// ------------- bf16x3 GEMM, 2-stage register pipeline -----------------------
#define G3_LOAD(ah, al, bh, bl, kk) do {                                      \
    _Pragma("unroll") for (int mt = 0; mt < 4; ++mt) {                        \
      size_t off = (size_t)(m0 + mt * 16 + l15) * K + (kk) + q8;              \
      ah[mt] = *(const bf16x8*)&Ah[off]; al[mt] = *(const bf16x8*)&Al[off]; } \
    _Pragma("unroll") for (int nt = 0; nt < 4; ++nt) {                        \
      size_t off = (size_t)(n0 + nt * 16 + l15) * K + (kk) + q8;              \
      bh[nt] = *(const bf16x8*)&Bh[off]; bl[nt] = *(const bf16x8*)&Bl[off]; } \
  } while (0)
#define G3_MFMA(ah, al, bh, bl) do {                                          \
    _Pragma("unroll") for (int mt = 0; mt < 4; ++mt)                          \
      _Pragma("unroll") for (int nt = 0; nt < 4; ++nt) {                      \
        acc[mt][nt] = __builtin_amdgcn_mfma_f32_16x16x32_bf16(ah[mt], bh[nt], acc[mt][nt], 0, 0, 0); \
        acc[mt][nt] = __builtin_amdgcn_mfma_f32_16x16x32_bf16(ah[mt], bl[nt], acc[mt][nt], 0, 0, 0); \
        acc[mt][nt] = __builtin_amdgcn_mfma_f32_16x16x32_bf16(al[mt], bh[nt], acc[mt][nt], 0, 0, 0); \
      }                                                                       \
  } while (0)

__global__ __launch_bounds__(64) void gemm3(
    const u16* __restrict__ Ah, const u16* __restrict__ Al,
    const u16* __restrict__ Bh, const u16* __restrict__ Bl,
    const float* __restrict__ bias, float* __restrict__ C,
    int K, int ldc) {
  const int m0 = blockIdx.y * 64, n0 = blockIdx.x * 64;
  const int lane = threadIdx.x, quad = lane >> 4, l15 = lane & 15;
  const int q8 = quad * 8;
  f32x4 acc[4][4];
#pragma unroll
  for (int mt = 0; mt < 4; ++mt)
#pragma unroll
    for (int nt = 0; nt < 4; ++nt) acc[mt][nt] = (f32x4){0.f, 0.f, 0.f, 0.f};
  bf16x8 ahA[4], alA[4], bhA[4], blA[4];
  bf16x8 ahB[4], alB[4], bhB[4], blB[4];
  G3_LOAD(ahA, alA, bhA, blA, 0);
  for (int k0 = 0; k0 < K; k0 += 64) {
    G3_LOAD(ahB, alB, bhB, blB, k0 + 32);
    G3_MFMA(ahA, alA, bhA, blA);
    if (k0 + 64 < K) G3_LOAD(ahA, alA, bhA, blA, k0 + 64);
    G3_MFMA(ahB, alB, bhB, blB);
  }
#pragma unroll
  for (int nt = 0; nt < 4; ++nt) {
    float bv = bias ? bias[n0 + nt * 16 + l15] : 0.f;
#pragma unroll
    for (int mt = 0; mt < 4; ++mt)
#pragma unroll
      for (int reg = 0; reg < 4; ++reg) {
        int row = m0 + mt * 16 + quad * 4 + reg;
        C[(size_t)row * ldc + n0 + nt * 16 + l15] = acc[mt][nt][reg] + bv;
      }
  }
}

// ---------------- RoPE on q -> bf16 [h][q][d], pre-scaled -------------------
__global__ __launch_bounds__(256) void rope_q(
    const float* __restrict__ qkv, const float* __restrict__ cs,
    const float* __restrict__ sn, u16* __restrict__ Qb) {
  int idx = blockIdx.x * 256 + threadIdx.x;   // NH*QL*64
  int dp = idx & 63;
  int q  = (idx >> 6) & 2047;
  int h  = idx >> 17;
  const float* base = qkv + (size_t)q * NQKV + h * HD;
  float x1 = base[dp], x2 = base[dp + 64];
  float c = cs[q * 64 + dp], s = sn[q * 64 + dp];
  u16* ob = Qb + ((size_t)h * QL + q) * HD;
  ob[dp]      = f2bf((x1 * c - x2 * s) * QSCALE);
  ob[dp + 64] = f2bf((x1 * s + x2 * c) * QSCALE);
}

// ---------------- K buffer -> bf16 [kvh][t][d] -------------------------------
__global__ __launch_bounds__(256) void build_k(
    const float* __restrict__ qkv, const float* __restrict__ k_hist,
    const float* __restrict__ cs, const float* __restrict__ sn,
    u16* __restrict__ Kb) {
  int idx = blockIdx.x * 256 + threadIdx.x;   // NKVH*KLEN*64
  int dp  = idx & 63;
  int tt  = (idx >> 6) & 4095;
  int kvh = idx >> 18;
  u16* ob = Kb + ((size_t)kvh * KLEN + tt) * HD;
  if (tt < HISTN) {
    const float* hb = k_hist + ((size_t)tt * NKVH + kvh) * HD;
    ob[dp] = f2bf(hb[dp]); ob[dp + 64] = f2bf(hb[dp + 64]);
  } else {
    int q = tt - HISTN;
    const float* base = qkv + (size_t)q * NQKV + HID + kvh * HD;
    float x1 = base[dp], x2 = base[dp + 64];
    float c = cs[q * 64 + dp], s = sn[q * 64 + dp];
    ob[dp]      = f2bf(x1 * c - x2 * s);
    ob[dp + 64] = f2bf(x1 * s + x2 * c);
  }
}

// -------- V^T buffer [kvh][VTROWS][t]: coalesced LDS-tile transpose ---------
// grid.x: 0..63 = 64x64 t-tiles; 64 = ones/zeros rows. grid.y: d-half. z: kvh.
__global__ __launch_bounds__(256) void build_vt(
    const float* __restrict__ qkv, const float* __restrict__ v_hist,
    u16* __restrict__ Vt) {
  const int kvh = blockIdx.z, t = threadIdx.x;
  if (blockIdx.x == 64) {   // rows 128..143: 128=ones, rest zero
    int r0 = 128 + blockIdx.y * 8;
    u16* base = Vt + ((size_t)kvh * VTROWS) * KLEN;
    for (int i = t; i < 8192; i += 256) {   // 8 rows x 1024 ushort4
      int row = r0 + (i >> 10), c4 = (i & 1023) * 4;
      u16 v = (row == 128) ? (u16)0x3F80 : (u16)0;
      ushort4 o4 = {v, v, v, v};
      *(ushort4*)&base[(size_t)row * KLEN + c4] = o4;
    }
    return;
  }
  __shared__ u16 T[64][68];
  const int t0 = blockIdx.x * 64, d0 = blockIdx.y * 64;
  const int r = t >> 4, c = (t & 15) * 4;
#pragma unroll
  for (int p = 0; p < 4; ++p) {
    int tt = t0 + p * 16 + r;
    float4 v;
    if (tt < HISTN) v = *(const float4*)&v_hist[((size_t)tt * NKVH + kvh) * HD + d0 + c];
    else            v = *(const float4*)&qkv[(size_t)(tt - HISTN) * NQKV + HID + 256 + kvh * HD + d0 + c];
    T[p * 16 + r][c + 0] = f2bf(v.x); T[p * 16 + r][c + 1] = f2bf(v.y);
    T[p * 16 + r][c + 2] = f2bf(v.z); T[p * 16 + r][c + 3] = f2bf(v.w);
  }
  __syncthreads();
  const int dr = t >> 2, cc0 = (t & 3) * 16;
#pragma unroll
  for (int i4 = 0; i4 < 4; ++i4) {
    ushort4 o4;
    o4.x = T[cc0 + i4 * 4 + 0][dr];
    o4.y = T[cc0 + i4 * 4 + 1][dr];
    o4.z = T[cc0 + i4 * 4 + 2][dr];
    o4.w = T[cc0 + i4 * 4 + 3][dr];
    *(ushort4*)&Vt[((size_t)kvh * VTROWS + d0 + dr) * KLEN + t0 + cc0 + i4 * 4] = o4;
  }
}

// -------- flash attention: max-free softmax, ones-row l, split-K ------------
// Block = 32 q-rows, 4 waves each own a contiguous quarter of the key range.
// No barriers / no shuffles in the K-loop. l computed via ones-row MFMA.
__global__ __launch_bounds__(256) void attn2(
    const u16* __restrict__ Q, const u16* __restrict__ K,
    const u16* __restrict__ Vt, u16* __restrict__ OH, u16* __restrict__ OL) {
  __shared__ __align__(16) char smem[37120];
  u16* sP = (u16*)smem;
  const int h = blockIdx.y, q0 = blockIdx.x * 32, kvh = h / 6;
  const int t = threadIdx.x, lane = t & 63, w = t >> 6;
  const int quad = lane >> 4, l15 = lane & 15, q8 = quad * 8;

  const u16* Qg = Q + ((size_t)h * QL + q0) * HD;
  bf16x8 Qf[2][4];
#pragma unroll
  for (int mt = 0; mt < 2; ++mt)
#pragma unroll
    for (int dc = 0; dc < 4; ++dc)
      Qf[mt][dc] = *(const bf16x8*)&Qg[(mt * 16 + l15) * HD + dc * 32 + q8];

  const int nsteps = (q0 + 32 + HISTN + 63) >> 6;
  const int bas = nsteps >> 2, rem = nsteps & 3;
  const int cnt = bas + (w < rem ? 1 : 0);
  const int s0  = w * bas + (w < rem ? w : rem);

  f32x4 o[2][8], ol[2];
#pragma unroll
  for (int mt = 0; mt < 2; ++mt) {
    ol[mt] = (f32x4){0.f, 0.f, 0.f, 0.f};
#pragma unroll
    for (int dt = 0; dt < 8; ++dt) o[mt][dt] = (f32x4){0.f, 0.f, 0.f, 0.f};
  }

  const u16* Kh = K + (size_t)kvh * KLEN * HD;
  const u16* Vh = Vt + (size_t)kvh * VTROWS * KLEN;
  u16* sPw0 = sP + w * 4608;

  for (int s = s0; s < s0 + cnt; ++s) {
    const int k0 = s << 6;
    u16* sPw = sPw0 + ((s & 1) ? 2304 : 0);
    f32x4 sc[2][4];
#pragma unroll
    for (int mt = 0; mt < 2; ++mt)
#pragma unroll
      for (int kt = 0; kt < 4; ++kt) sc[mt][kt] = (f32x4){0.f, 0.f, 0.f, 0.f};
#pragma unroll
    for (int dc = 0; dc < 4; ++dc) {
      bf16x8 bK[4];
#pragma unroll
      for (int kt = 0; kt < 4; ++kt)
        bK[kt] = *(const bf16x8*)&Kh[(size_t)(k0 + kt * 16 + l15) * HD + dc * 32 + q8];
#pragma unroll
      for (int mt = 0; mt < 2; ++mt)
#pragma unroll
        for (int kt = 0; kt < 4; ++kt)
          sc[mt][kt] = __builtin_amdgcn_mfma_f32_16x16x32_bf16(Qf[mt][dc], bK[kt], sc[mt][kt], 0, 0, 0);
    }
    if (k0 + 63 - HISTN > q0) {   // causal boundary inside this step
#pragma unroll
      for (int mt = 0; mt < 2; ++mt)
#pragma unroll
        for (int kt = 0; kt < 4; ++kt) {
          int kg = k0 + kt * 16 + l15;
#pragma unroll
          for (int reg = 0; reg < 4; ++reg)
            if (kg > q0 + mt * 16 + quad * 4 + reg + HISTN) sc[mt][kt][reg] = -INFINITY;
        }
    }
    // exp (no max subtraction -- scores bounded) + P -> LDS (A-layout rows)
#pragma unroll
    for (int mt = 0; mt < 2; ++mt)
#pragma unroll
      for (int reg = 0; reg < 4; ++reg)
#pragma unroll
        for (int kt = 0; kt < 4; ++kt) {
          float p = __expf(sc[mt][kt][reg]);
          sPw[(mt * 16 + quad * 4 + reg) * 72 + kt * 16 + l15] = f2bf(p);
        }
    // PV (+ ones tile dt=8 accumulates l)
#pragma unroll
    for (int kc = 0; kc < 2; ++kc) {
      bf16x8 aP[2];
#pragma unroll
      for (int mt = 0; mt < 2; ++mt)
        aP[mt] = *(const bf16x8*)&sPw[(mt * 16 + l15) * 72 + kc * 32 + q8];
#pragma unroll
      for (int dt = 0; dt < 9; ++dt) {
        bf16x8 bV = *(const bf16x8*)&Vh[(size_t)(dt * 16 + l15) * KLEN + k0 + kc * 32 + q8];
        if (dt < 8) {
#pragma unroll
          for (int mt = 0; mt < 2; ++mt)
            o[mt][dt] = __builtin_amdgcn_mfma_f32_16x16x32_bf16(aP[mt], bV, o[mt][dt], 0, 0, 0);
        } else {
#pragma unroll
          for (int mt = 0; mt < 2; ++mt)
            ol[mt] = __builtin_amdgcn_mfma_f32_16x16x32_bf16(aP[mt], bV, ol[mt], 0, 0, 0);
        }
      }
    }
  }

  // ---- merge: plain sums (max-free) ----
  __syncthreads();                       // sP dead; alias combine buffers
  float* cO   = (float*)smem;            // [2][32][132]
  float* cL   = (float*)(smem + 33792);  // [2][32]
  float* cInv = (float*)(smem + 34048);  // [32]
  if (w & 1) {
    int buf = w >> 1;
#pragma unroll
    for (int mt = 0; mt < 2; ++mt)
#pragma unroll
      for (int reg = 0; reg < 4; ++reg) {
        int r = mt * 16 + quad * 4 + reg;
        if (l15 == 0) cL[buf * 32 + r] = ol[mt][reg];
#pragma unroll
        for (int dt = 0; dt < 8; ++dt)
          cO[(buf * 32 + r) * 132 + dt * 16 + l15] = o[mt][dt][reg];
      }
  }
  __syncthreads();
  if (!(w & 1)) {
    int buf = w >> 1;
#pragma unroll
    for (int mt = 0; mt < 2; ++mt)
#pragma unroll
      for (int reg = 0; reg < 4; ++reg) {
        int r = mt * 16 + quad * 4 + reg;
        if (l15 == 0) ol[mt][reg] += cL[buf * 32 + r];
#pragma unroll
        for (int dt = 0; dt < 8; ++dt)
          o[mt][dt][reg] += cO[(buf * 32 + r) * 132 + dt * 16 + l15];
      }
  }
  __syncthreads();
  if (w == 2) {
#pragma unroll
    for (int mt = 0; mt < 2; ++mt)
#pragma unroll
      for (int reg = 0; reg < 4; ++reg) {
        int r = mt * 16 + quad * 4 + reg;
        if (l15 == 0) cL[r] = ol[mt][reg];
#pragma unroll
        for (int dt = 0; dt < 8; ++dt)
          cO[r * 132 + dt * 16 + l15] = o[mt][dt][reg];
      }
  }
  __syncthreads();
  if (w == 0) {
#pragma unroll
    for (int mt = 0; mt < 2; ++mt)
#pragma unroll
      for (int reg = 0; reg < 4; ++reg) {
        int r = mt * 16 + quad * 4 + reg;
        if (l15 == 0) cInv[r] = 1.f / (ol[mt][reg] + cL[r]);
      }
#pragma unroll
    for (int mt = 0; mt < 2; ++mt)
#pragma unroll
      for (int reg = 0; reg < 4; ++reg) {
        int r = mt * 16 + quad * 4 + reg;
        float inv = cInv[r];
        int row = q0 + r;
#pragma unroll
        for (int dt = 0; dt < 8; ++dt) {
          float val = (o[mt][dt][reg] + cO[r * 132 + dt * 16 + l15]) * inv;
          u16 hv = f2bf(val);
          size_t oi = (size_t)row * HID + h * HD + dt * 16 + l15;
          OH[oi] = hv;
          OL[oi] = f2bf(val - bf2f(hv));
        }
      }
  }
}

extern "C" void kernel_launch(void* const* d_in, const int* in_sizes, int n_in,
                              void* d_out, int out_size, void* d_ws, size_t ws_size,
                              hipStream_t stream) {
  (void)in_sizes; (void)n_in; (void)out_size; (void)ws_size;
  const float* x      = (const float*)d_in[0];
  const float* Wq     = (const float*)d_in[1];
  const float* bq     = (const float*)d_in[2];
  const float* Wk     = (const float*)d_in[3];
  const float* bk     = (const float*)d_in[4];
  const float* Wv     = (const float*)d_in[5];
  const float* bv     = (const float*)d_in[6];
  const float* Wo     = (const float*)d_in[7];
  const float* k_hist = (const float*)d_in[8];
  const float* v_hist = (const float*)d_in[9];
  const float* fcos   = (const float*)d_in[10];
  const float* fsin   = (const float*)d_in[11];
  float* out = (float*)d_out;

  char* p = (char*)d_ws;
  float* qkv   = (float*)p;  p += (size_t)QL * NQKV * 4;            // 16.78 MB
  u16*   Qb    = (u16*)p;    p += (size_t)NH * QL * HD * 2;         // 6.29
  u16*   Kb    = (u16*)p;    p += (size_t)NKVH * KLEN * HD * 2;     // 2.10
  u16*   Vtb   = (u16*)p;    p += (size_t)NKVH * VTROWS * KLEN * 2; // 2.36
  u16*   xh    = (u16*)p;    p += (size_t)QL * HID * 2;             // 6.29 (alias attnH)
  u16*   xl    = (u16*)p;    p += (size_t)QL * HID * 2;             // 6.29 (alias attnL)
  u16*   WqkvH = (u16*)p;    p += (size_t)NQKV * HID * 2;           // 6.29 (alias WoH)
  u16*   WqkvL = (u16*)p;    p += (size_t)NQKV * HID * 2;           // 6.29 (alias WoL)
  float* bcat  = (float*)p;  p += (size_t)NQKV * 4;                 // ~52.7 MB total
  u16* attnH = xh;  u16* attnL = xl;    // x dead after QKV gemm
  u16* WoH = WqkvH; u16* WoL = WqkvL;   // Wqkv dead after QKV gemm

  splitf <<<3072, 256, 0, stream>>>(x, xh, xl, (int)((size_t)QL * HID / 4));
  split_T<<<dim3(24, 24), 256, 0, stream>>>(Wq, WqkvH, WqkvL, HID, HID);
  split_T<<<dim3(4, 24), 256, 0, stream>>>(Wk, WqkvH + (size_t)HID * HID, WqkvL + (size_t)HID * HID, HID, 256);
  split_T<<<dim3(4, 24), 256, 0, stream>>>(Wv, WqkvH + (size_t)(HID + 256) * HID, WqkvL + (size_t)(HID + 256) * HID, HID, 256);
  bcat_k <<<8, 256, 0, stream>>>(bq, bk, bv, bcat);

  gemm3<<<dim3(32, 32), 64, 0, stream>>>(xh, xl, WqkvH, WqkvL, bcat, qkv, HID, NQKV);

  split_T<<<dim3(24, 24), 256, 0, stream>>>(Wo, WoH, WoL, HID, HID);  // after QKV gemm

  rope_q  <<<6144, 256, 0, stream>>>(qkv, fcos, fsin, Qb);
  build_k <<<2048, 256, 0, stream>>>(qkv, k_hist, fcos, fsin, Kb);
  build_vt<<<dim3(65, 2, 2), 256, 0, stream>>>(qkv, v_hist, Vtb);

  attn2<<<dim3(64, 12), 256, 0, stream>>>(Qb, Kb, Vtb, attnH, attnL);

  gemm3<<<dim3(24, 32), 64, 0, stream>>>(attnH, attnL, WoH, WoL, nullptr, out, HID, HID);
}

// Round 6
// 510.280 us; speedup vs baseline: 3.7702x; 1.0422x over previous
//
#include <hip/hip_runtime.h>
#include <math.h>

#define QL 2048
#define HISTN 2048
#define KLEN 4096
#define NH 12
#define NKVH 2
#define HD 128
#define HID 1536
#define NQKV 2048   // 1536 q + 256 k + 256 v
#define VTROWS 144  // 128 d + 1 ones + 15 zeros
#define QSCALE 0.08838834764831845f  // 1/sqrt(128)

typedef unsigned short u16;
typedef short bf16x8 __attribute__((ext_vector_type(8)));
typedef float f32x4 __attribute__((ext_vector_type(4)));

__device__ __forceinline__ u16 f2bf(float f) {
  union { float f; unsigned u; } v; v.f = f;
  unsigned r = v.u + 0x7FFFu + ((v.u >> 16) & 1u);
  return (u16)(r >> 16);
}
__device__ __forceinline__ float bf2f(u16 h) {
  union { unsigned u; float f; } v; v.u = ((unsigned)h) << 16; return v.f;
}

// ---------- split_T tile helper: W[K][N] 64x64 tile -> Bt[N][K] hi/lo -------
__device__ __forceinline__ void split_T_tile(const float* __restrict__ W,
    u16* __restrict__ BtH, u16* __restrict__ BtL, int K, int N, int k0, int n0,
    int t, float (*T)[65]) {
  const int r = t >> 4, c = (t & 15) * 4;
#pragma unroll
  for (int p = 0; p < 4; ++p) {
    float4 v = *(const float4*)&W[(size_t)(k0 + p * 16 + r) * N + n0 + c];
    T[p * 16 + r][c + 0] = v.x; T[p * 16 + r][c + 1] = v.y;
    T[p * 16 + r][c + 2] = v.z; T[p * 16 + r][c + 3] = v.w;
  }
  __syncthreads();
  const int rr = t >> 2, cc0 = (t & 3) * 16;
#pragma unroll
  for (int i4 = 0; i4 < 4; ++i4) {
    float f0 = T[cc0 + i4 * 4 + 0][rr];
    float f1 = T[cc0 + i4 * 4 + 1][rr];
    float f2 = T[cc0 + i4 * 4 + 2][rr];
    float f3 = T[cc0 + i4 * 4 + 3][rr];
    ushort4 h, l;
    h.x = f2bf(f0); l.x = f2bf(f0 - bf2f(h.x));
    h.y = f2bf(f1); l.y = f2bf(f1 - bf2f(h.y));
    h.z = f2bf(f2); l.z = f2bf(f2 - bf2f(h.z));
    h.w = f2bf(f3); l.w = f2bf(f3 - bf2f(h.w));
    size_t off = (size_t)(n0 + rr) * K + k0 + cc0 + i4 * 4;
    *(ushort4*)&BtH[off] = h;
    *(ushort4*)&BtL[off] = l;
  }
}

// ---------- fused prep: splitf(x) + split_T(Wq,Wk,Wv,Wo) + bias concat ------
__global__ __launch_bounds__(256) void prep(
    const float* __restrict__ x,  const float* __restrict__ Wq,
    const float* __restrict__ Wk, const float* __restrict__ Wv,
    const float* __restrict__ Wo, const float* __restrict__ bq,
    const float* __restrict__ bk, const float* __restrict__ bv,
    u16* __restrict__ xh, u16* __restrict__ xl,
    u16* __restrict__ WqkvH, u16* __restrict__ WqkvL,
    u16* __restrict__ WoH, u16* __restrict__ WoL, float* __restrict__ bcat) {
  __shared__ float T[64][65];
  const int bx = blockIdx.x, t = threadIdx.x;
  if (bx < 3072) {                       // splitf: 786432 float4s
    int i = bx * 256 + t;
    float4 v = ((const float4*)x)[i];
    ushort4 h, l;
    h.x = f2bf(v.x); l.x = f2bf(v.x - bf2f(h.x));
    h.y = f2bf(v.y); l.y = f2bf(v.y - bf2f(h.y));
    h.z = f2bf(v.z); l.z = f2bf(v.z - bf2f(h.z));
    h.w = f2bf(v.w); l.w = f2bf(v.w - bf2f(h.w));
    ((ushort4*)xh)[i] = h;
    ((ushort4*)xl)[i] = l;
  } else if (bx < 3648) {                // Wq: 24 n-tiles x 24 k-tiles
    int b = bx - 3072;
    split_T_tile(Wq, WqkvH, WqkvL, HID, HID, (b / 24) * 64, (b % 24) * 64, t, T);
  } else if (bx < 3744) {                // Wk: 4 x 24
    int b = bx - 3648;
    split_T_tile(Wk, WqkvH + (size_t)HID * HID, WqkvL + (size_t)HID * HID,
                 HID, 256, (b / 4) * 64, (b % 4) * 64, t, T);
  } else if (bx < 3840) {                // Wv: 4 x 24
    int b = bx - 3744;
    split_T_tile(Wv, WqkvH + (size_t)(HID + 256) * HID, WqkvL + (size_t)(HID + 256) * HID,
                 HID, 256, (b / 4) * 64, (b % 4) * 64, t, T);
  } else if (bx < 4416) {                // Wo: 24 x 24
    int b = bx - 3840;
    split_T_tile(Wo, WoH, WoL, HID, HID, (b / 24) * 64, (b % 24) * 64, t, T);
  } else {                               // bias concat: 8 blocks
    int i = (bx - 4416) * 256 + t;
    bcat[i] = (i < HID) ? bq[i] : (i < HID + 256 ? bk[i - HID] : bv[i - HID - 256]);
  }
}

// ------------- bf16x3 GEMM, 2-stage register pipeline (unchanged) -----------
#define G3_LOAD(ah, al, bh, bl, kk) do {                                      \
    _Pragma("unroll") for (int mt = 0; mt < 4; ++mt) {                        \
      size_t off = (size_t)(m0 + mt * 16 + l15) * K + (kk) + q8;              \
      ah[mt] = *(const bf16x8*)&Ah[off]; al[mt] = *(const bf16x8*)&Al[off]; } \
    _Pragma("unroll") for (int nt = 0; nt < 4; ++nt) {                        \
      size_t off = (size_t)(n0 + nt * 16 + l15) * K + (kk) + q8;              \
      bh[nt] = *(const bf16x8*)&Bh[off]; bl[nt] = *(const bf16x8*)&Bl[off]; } \
  } while (0)
#define G3_MFMA(ah, al, bh, bl) do {                                          \
    _Pragma("unroll") for (int mt = 0; mt < 4; ++mt)                          \
      _Pragma("unroll") for (int nt = 0; nt < 4; ++nt) {                      \
        acc[mt][nt] = __builtin_amdgcn_mfma_f32_16x16x32_bf16(ah[mt], bh[nt], acc[mt][nt], 0, 0, 0); \
        acc[mt][nt] = __builtin_amdgcn_mfma_f32_16x16x32_bf16(ah[mt], bl[nt], acc[mt][nt], 0, 0, 0); \
        acc[mt][nt] = __builtin_amdgcn_mfma_f32_16x16x32_bf16(al[mt], bh[nt], acc[mt][nt], 0, 0, 0); \
      }                                                                       \
  } while (0)

__global__ __launch_bounds__(64) void gemm3(
    const u16* __restrict__ Ah, const u16* __restrict__ Al,
    const u16* __restrict__ Bh, const u16* __restrict__ Bl,
    const float* __restrict__ bias, float* __restrict__ C,
    int K, int ldc) {
  const int m0 = blockIdx.y * 64, n0 = blockIdx.x * 64;
  const int lane = threadIdx.x, quad = lane >> 4, l15 = lane & 15;
  const int q8 = quad * 8;
  f32x4 acc[4][4];
#pragma unroll
  for (int mt = 0; mt < 4; ++mt)
#pragma unroll
    for (int nt = 0; nt < 4; ++nt) acc[mt][nt] = (f32x4){0.f, 0.f, 0.f, 0.f};
  bf16x8 ahA[4], alA[4], bhA[4], blA[4];
  bf16x8 ahB[4], alB[4], bhB[4], blB[4];
  G3_LOAD(ahA, alA, bhA, blA, 0);
  for (int k0 = 0; k0 < K; k0 += 64) {
    G3_LOAD(ahB, alB, bhB, blB, k0 + 32);
    G3_MFMA(ahA, alA, bhA, blA);
    if (k0 + 64 < K) G3_LOAD(ahA, alA, bhA, blA, k0 + 64);
    G3_MFMA(ahB, alB, bhB, blB);
  }
#pragma unroll
  for (int nt = 0; nt < 4; ++nt) {
    float bv = bias ? bias[n0 + nt * 16 + l15] : 0.f;
#pragma unroll
    for (int mt = 0; mt < 4; ++mt)
#pragma unroll
      for (int reg = 0; reg < 4; ++reg) {
        int row = m0 + mt * 16 + quad * 4 + reg;
        C[(size_t)row * ldc + n0 + nt * 16 + l15] = acc[mt][nt][reg] + bv;
      }
  }
}

// ---------- fused post: rope_q + build_k + build_vt -------------------------
__global__ __launch_bounds__(256) void post(
    const float* __restrict__ qkv, const float* __restrict__ k_hist,
    const float* __restrict__ v_hist, const float* __restrict__ cs,
    const float* __restrict__ sn, u16* __restrict__ Qb, u16* __restrict__ Kb,
    u16* __restrict__ Vt) {
  __shared__ u16 T[64][68];
  const int bx = blockIdx.x, t = threadIdx.x;
  if (bx < 1536) {                       // rope_q: NH*QL*16 float4-pairs
    int idx = bx * 256 + t;
    int dp4 = (idx & 15) * 4;
    int q   = (idx >> 4) & 2047;
    int h   = idx >> 15;
    const float* base = qkv + (size_t)q * NQKV + h * HD;
    float4 x1 = *(const float4*)&base[dp4];
    float4 x2 = *(const float4*)&base[dp4 + 64];
    float4 c = *(const float4*)&cs[q * 64 + dp4];
    float4 s = *(const float4*)&sn[q * 64 + dp4];
    u16* ob = Qb + ((size_t)h * QL + q) * HD;
    ushort4 o1, o2;
    o1.x = f2bf((x1.x * c.x - x2.x * s.x) * QSCALE);
    o1.y = f2bf((x1.y * c.y - x2.y * s.y) * QSCALE);
    o1.z = f2bf((x1.z * c.z - x2.z * s.z) * QSCALE);
    o1.w = f2bf((x1.w * c.w - x2.w * s.w) * QSCALE);
    o2.x = f2bf((x1.x * s.x + x2.x * c.x) * QSCALE);
    o2.y = f2bf((x1.y * s.y + x2.y * c.y) * QSCALE);
    o2.z = f2bf((x1.z * s.z + x2.z * c.z) * QSCALE);
    o2.w = f2bf((x1.w * s.w + x2.w * c.w) * QSCALE);
    *(ushort4*)&ob[dp4]      = o1;
    *(ushort4*)&ob[dp4 + 64] = o2;
  } else if (bx < 2048) {                // build_k: NKVH*KLEN*16
    int idx = (bx - 1536) * 256 + t;
    int dp4 = (idx & 15) * 4;
    int tt  = (idx >> 4) & 4095;
    int kvh = idx >> 16;
    u16* ob = Kb + ((size_t)kvh * KLEN + tt) * HD;
    if (tt < HISTN) {
      const float* hb = k_hist + ((size_t)tt * NKVH + kvh) * HD;
      float4 a = *(const float4*)&hb[dp4];
      float4 b = *(const float4*)&hb[dp4 + 64];
      ushort4 o1, o2;
      o1.x = f2bf(a.x); o1.y = f2bf(a.y); o1.z = f2bf(a.z); o1.w = f2bf(a.w);
      o2.x = f2bf(b.x); o2.y = f2bf(b.y); o2.z = f2bf(b.z); o2.w = f2bf(b.w);
      *(ushort4*)&ob[dp4]      = o1;
      *(ushort4*)&ob[dp4 + 64] = o2;
    } else {
      int q = tt - HISTN;
      const float* base = qkv + (size_t)q * NQKV + HID + kvh * HD;
      float4 x1 = *(const float4*)&base[dp4];
      float4 x2 = *(const float4*)&base[dp4 + 64];
      float4 c = *(const float4*)&cs[q * 64 + dp4];
      float4 s = *(const float4*)&sn[q * 64 + dp4];
      ushort4 o1, o2;
      o1.x = f2bf(x1.x * c.x - x2.x * s.x);
      o1.y = f2bf(x1.y * c.y - x2.y * s.y);
      o1.z = f2bf(x1.z * c.z - x2.z * s.z);
      o1.w = f2bf(x1.w * c.w - x2.w * s.w);
      o2.x = f2bf(x1.x * s.x + x2.x * c.x);
      o2.y = f2bf(x1.y * s.y + x2.y * c.y);
      o2.z = f2bf(x1.z * s.z + x2.z * c.z);
      o2.w = f2bf(x1.w * s.w + x2.w * c.w);
      *(ushort4*)&ob[dp4]      = o1;
      *(ushort4*)&ob[dp4 + 64] = o2;
    }
  } else {                               // build_vt: 260 blocks
    int b = bx - 2048;
    int xt = b % 65, rest = b / 65;
    int dh = rest & 1, kvh = rest >> 1;
    if (xt == 64) {                      // rows 128..143: 128=ones, rest zero
      int r0 = 128 + dh * 8;
      u16* base = Vt + ((size_t)kvh * VTROWS) * KLEN;
      for (int i = t; i < 8192; i += 256) {
        int row = r0 + (i >> 10), c4 = (i & 1023) * 4;
        u16 v = (row == 128) ? (u16)0x3F80 : (u16)0;
        ushort4 o4 = {v, v, v, v};
        *(ushort4*)&base[(size_t)row * KLEN + c4] = o4;
      }
      return;
    }
    const int t0 = xt * 64, d0 = dh * 64;
    const int r = t >> 4, c = (t & 15) * 4;
#pragma unroll
    for (int p = 0; p < 4; ++p) {
      int tt = t0 + p * 16 + r;
      float4 v;
      if (tt < HISTN) v = *(const float4*)&v_hist[((size_t)tt * NKVH + kvh) * HD + d0 + c];
      else            v = *(const float4*)&qkv[(size_t)(tt - HISTN) * NQKV + HID + 256 + kvh * HD + d0 + c];
      T[p * 16 + r][c + 0] = f2bf(v.x); T[p * 16 + r][c + 1] = f2bf(v.y);
      T[p * 16 + r][c + 2] = f2bf(v.z); T[p * 16 + r][c + 3] = f2bf(v.w);
    }
    __syncthreads();
    const int dr = t >> 2, cc0 = (t & 3) * 16;
#pragma unroll
    for (int i4 = 0; i4 < 4; ++i4) {
      ushort4 o4;
      o4.x = T[cc0 + i4 * 4 + 0][dr];
      o4.y = T[cc0 + i4 * 4 + 1][dr];
      o4.z = T[cc0 + i4 * 4 + 2][dr];
      o4.w = T[cc0 + i4 * 4 + 3][dr];
      *(ushort4*)&Vt[((size_t)kvh * VTROWS + d0 + dr) * KLEN + t0 + cc0 + i4 * 4] = o4;
    }
  }
}

// -------- flash attention: 512 thr / 8 waves / 8-way split-K ----------------
// Max-free softmax, ones-row l, no barriers/shuffles in K-loop.
// LDS budget: 8 waves x 2304 u16 P-patch = 36864 B exactly (single-buffered;
// R5's double-buffer overflowed LDS -> waves 4-7 dropped writes/zero reads).
#define MWRITE(buf) do {                                                      \
    _Pragma("unroll") for (int mt = 0; mt < 2; ++mt)                          \
      _Pragma("unroll") for (int reg = 0; reg < 4; ++reg) {                   \
        int r = mt * 16 + quad * 4 + reg;                                     \
        if (l15 == 0) cL[(buf) * 32 + r] = ol[mt][reg];                       \
        _Pragma("unroll") for (int dt = 0; dt < 8; ++dt)                      \
          cO[((buf) * 32 + r) * 132 + dt * 16 + l15] = o[mt][dt][reg];        \
      }                                                                       \
  } while (0)
#define MMERGE(buf) do {                                                      \
    _Pragma("unroll") for (int mt = 0; mt < 2; ++mt)                          \
      _Pragma("unroll") for (int reg = 0; reg < 4; ++reg) {                   \
        int r = mt * 16 + quad * 4 + reg;                                     \
        if (l15 == 0) ol[mt][reg] += cL[(buf) * 32 + r];                      \
        _Pragma("unroll") for (int dt = 0; dt < 8; ++dt)                      \
          o[mt][dt][reg] += cO[((buf) * 32 + r) * 132 + dt * 16 + l15];       \
      }                                                                       \
  } while (0)

__global__ __launch_bounds__(512) void attn3(
    const u16* __restrict__ Q, const u16* __restrict__ K,
    const u16* __restrict__ Vt, u16* __restrict__ OH, u16* __restrict__ OL) {
  __shared__ __align__(16) char smem[36864];
  u16* sP = (u16*)smem;
  const int h = blockIdx.y;
  const int bx = blockIdx.x;
  const int qt = (bx & 1) ? (63 - (bx >> 1)) : (bx >> 1);  // long/short pairing
  const int q0 = qt * 32, kvh = h / 6;
  const int t = threadIdx.x, lane = t & 63, w = t >> 6;    // w in 0..7
  const int quad = lane >> 4, l15 = lane & 15, q8 = quad * 8;

  const u16* Qg = Q + ((size_t)h * QL + q0) * HD;
  bf16x8 Qf[2][4];
#pragma unroll
  for (int mt = 0; mt < 2; ++mt)
#pragma unroll
    for (int dc = 0; dc < 4; ++dc)
      Qf[mt][dc] = *(const bf16x8*)&Qg[(mt * 16 + l15) * HD + dc * 32 + q8];

  const int nsteps = (q0 + 32 + HISTN + 63) >> 6;
  const int bas = nsteps >> 3, rem = nsteps & 7;
  const int cnt = bas + (w < rem ? 1 : 0);
  const int s0  = w * bas + (w < rem ? w : rem);

  f32x4 o[2][8], ol[2];
#pragma unroll
  for (int mt = 0; mt < 2; ++mt) {
    ol[mt] = (f32x4){0.f, 0.f, 0.f, 0.f};
#pragma unroll
    for (int dt = 0; dt < 8; ++dt) o[mt][dt] = (f32x4){0.f, 0.f, 0.f, 0.f};
  }

  const u16* Kh = K + (size_t)kvh * KLEN * HD;
  const u16* Vh = Vt + (size_t)kvh * VTROWS * KLEN;
  u16* sPw = sP + w * 2304;   // single 32x72 u16 patch per wave

  for (int s = s0; s < s0 + cnt; ++s) {
    const int k0 = s << 6;
    f32x4 sc[2][4];
#pragma unroll
    for (int mt = 0; mt < 2; ++mt)
#pragma unroll
      for (int kt = 0; kt < 4; ++kt) sc[mt][kt] = (f32x4){0.f, 0.f, 0.f, 0.f};
#pragma unroll
    for (int dc = 0; dc < 4; ++dc) {
      bf16x8 bK[4];
#pragma unroll
      for (int kt = 0; kt < 4; ++kt)
        bK[kt] = *(const bf16x8*)&Kh[(size_t)(k0 + kt * 16 + l15) * HD + dc * 32 + q8];
#pragma unroll
      for (int mt = 0; mt < 2; ++mt)
#pragma unroll
        for (int kt = 0; kt < 4; ++kt)
          sc[mt][kt] = __builtin_amdgcn_mfma_f32_16x16x32_bf16(Qf[mt][dc], bK[kt], sc[mt][kt], 0, 0, 0);
    }
    if (k0 + 63 - HISTN > q0) {   // causal boundary inside this step
#pragma unroll
      for (int mt = 0; mt < 2; ++mt)
#pragma unroll
        for (int kt = 0; kt < 4; ++kt) {
          int kg = k0 + kt * 16 + l15;
#pragma unroll
          for (int reg = 0; reg < 4; ++reg)
            if (kg > q0 + mt * 16 + quad * 4 + reg + HISTN) sc[mt][kt][reg] = -INFINITY;
        }
    }
#pragma unroll
    for (int mt = 0; mt < 2; ++mt)
#pragma unroll
      for (int reg = 0; reg < 4; ++reg)
#pragma unroll
        for (int kt = 0; kt < 4; ++kt) {
          float p = __expf(sc[mt][kt][reg]);
          sPw[(mt * 16 + quad * 4 + reg) * 72 + kt * 16 + l15] = f2bf(p);
        }
#pragma unroll
    for (int kc = 0; kc < 2; ++kc) {
      bf16x8 aP[2];
#pragma unroll
      for (int mt = 0; mt < 2; ++mt)
        aP[mt] = *(const bf16x8*)&sPw[(mt * 16 + l15) * 72 + kc * 32 + q8];
#pragma unroll
      for (int dt = 0; dt < 9; ++dt) {
        bf16x8 bV = *(const bf16x8*)&Vh[(size_t)(dt * 16 + l15) * KLEN + k0 + kc * 32 + q8];
        if (dt < 8) {
#pragma unroll
          for (int mt = 0; mt < 2; ++mt)
            o[mt][dt] = __builtin_amdgcn_mfma_f32_16x16x32_bf16(aP[mt], bV, o[mt][dt], 0, 0, 0);
        } else {
#pragma unroll
          for (int mt = 0; mt < 2; ++mt)
            ol[mt] = __builtin_amdgcn_mfma_f32_16x16x32_bf16(aP[mt], bV, ol[mt], 0, 0, 0);
        }
      }
    }
  }

  // ---- 8-wave merge: plain sums through 2 LDS buffers ----
  __syncthreads();                       // sP dead; alias combine buffers
  float* cO   = (float*)smem;            // [2][32][132]
  float* cL   = (float*)(smem + 33792);  // [2][32]
  float* cInv = (float*)(smem + 34048);  // [32]
  if (w == 1) MWRITE(0);
  if (w == 3) MWRITE(1);
  __syncthreads();
  if (w == 0) MMERGE(0);
  if (w == 2) MMERGE(1);
  __syncthreads();
  if (w == 5) MWRITE(0);
  if (w == 7) MWRITE(1);
  __syncthreads();
  if (w == 4) MMERGE(0);
  if (w == 6) MMERGE(1);
  __syncthreads();
  if (w == 2) MWRITE(0);
  if (w == 6) MWRITE(1);
  __syncthreads();
  if (w == 0) MMERGE(0);
  if (w == 4) MMERGE(1);
  __syncthreads();
  if (w == 4) MWRITE(0);
  __syncthreads();
  if (w == 0) {
    MMERGE(0);
#pragma unroll
    for (int mt = 0; mt < 2; ++mt)
#pragma unroll
      for (int reg = 0; reg < 4; ++reg) {
        int r = mt * 16 + quad * 4 + reg;
        if (l15 == 0) cInv[r] = 1.f / ol[mt][reg];
      }
#pragma unroll
    for (int mt = 0; mt < 2; ++mt)
#pragma unroll
      for (int reg = 0; reg < 4; ++reg) {
        int r = mt * 16 + quad * 4 + reg;
        float inv = cInv[r];
        int row = q0 + r;
#pragma unroll
        for (int dt = 0; dt < 8; ++dt) {
          float val = o[mt][dt][reg] * inv;
          u16 hv = f2bf(val);
          size_t oi = (size_t)row * HID + h * HD + dt * 16 + l15;
          OH[oi] = hv;
          OL[oi] = f2bf(val - bf2f(hv));
        }
      }
  }
}

extern "C" void kernel_launch(void* const* d_in, const int* in_sizes, int n_in,
                              void* d_out, int out_size, void* d_ws, size_t ws_size,
                              hipStream_t stream) {
  (void)in_sizes; (void)n_in; (void)out_size; (void)ws_size;
  const float* x      = (const float*)d_in[0];
  const float* Wq     = (const float*)d_in[1];
  const float* bq     = (const float*)d_in[2];
  const float* Wk     = (const float*)d_in[3];
  const float* bk     = (const float*)d_in[4];
  const float* Wv     = (const float*)d_in[5];
  const float* bv     = (const float*)d_in[6];
  const float* Wo     = (const float*)d_in[7];
  const float* k_hist = (const float*)d_in[8];
  const float* v_hist = (const float*)d_in[9];
  const float* fcos   = (const float*)d_in[10];
  const float* fsin   = (const float*)d_in[11];
  float* out = (float*)d_out;

  char* p = (char*)d_ws;
  float* qkv   = (float*)p;  p += (size_t)QL * NQKV * 4;
  u16*   Qb    = (u16*)p;    p += (size_t)NH * QL * HD * 2;
  u16*   Kb    = (u16*)p;    p += (size_t)NKVH * KLEN * HD * 2;
  u16*   Vtb   = (u16*)p;    p += (size_t)NKVH * VTROWS * KLEN * 2;
  u16*   xh    = (u16*)p;    p += (size_t)QL * HID * 2;             // alias attnH
  u16*   xl    = (u16*)p;    p += (size_t)QL * HID * 2;             // alias attnL
  u16*   WqkvH = (u16*)p;    p += (size_t)NQKV * HID * 2;
  u16*   WqkvL = (u16*)p;    p += (size_t)NQKV * HID * 2;
  u16*   WoH   = (u16*)p;    p += (size_t)HID * HID * 2;
  u16*   WoL   = (u16*)p;    p += (size_t)HID * HID * 2;
  float* bcat  = (float*)p;  p += (size_t)NQKV * 4;                 // ~64 MB total
  u16* attnH = xh;  u16* attnL = xl;    // x dead after QKV gemm

  prep<<<4424, 256, 0, stream>>>(x, Wq, Wk, Wv, Wo, bq, bk, bv,
                                 xh, xl, WqkvH, WqkvL, WoH, WoL, bcat);
  gemm3<<<dim3(32, 32), 64, 0, stream>>>(xh, xl, WqkvH, WqkvL, bcat, qkv, HID, NQKV);
  post<<<2308, 256, 0, stream>>>(qkv, k_hist, v_hist, fcos, fsin, Qb, Kb, Vtb);
  attn3<<<dim3(64, 12), 512, 0, stream>>>(Qb, Kb, Vtb, attnH, attnL);
  gemm3<<<dim3(24, 32), 64, 0, stream>>>(attnH, attnL, WoH, WoL, nullptr, out, HID, HID);
}

// Round 7
// 503.934 us; speedup vs baseline: 3.8177x; 1.0126x over previous
//
#include <hip/hip_runtime.h>
#include <math.h>

#define QL 2048
#define HISTN 2048
#define KLEN 4096
#define NH 12
#define NKVH 2
#define HD 128
#define HID 1536
#define NQKV 2048   // 1536 q + 256 k + 256 v
#define VTROWS 144  // 128 d + 1 ones + 15 zeros
#define QSCALE 0.08838834764831845f  // 1/sqrt(128)

typedef unsigned short u16;
typedef short bf16x8 __attribute__((ext_vector_type(8)));
typedef float f32x4 __attribute__((ext_vector_type(4)));

__device__ __forceinline__ u16 f2bf(float f) {
  union { float f; unsigned u; } v; v.f = f;
  unsigned r = v.u + 0x7FFFu + ((v.u >> 16) & 1u);
  return (u16)(r >> 16);
}
__device__ __forceinline__ float bf2f(u16 h) {
  union { unsigned u; float f; } v; v.u = ((unsigned)h) << 16; return v.f;
}

// ---------- split_T tile helper: W[K][N] 64x64 tile -> Bt[N][K] hi/lo -------
__device__ __forceinline__ void split_T_tile(const float* __restrict__ W,
    u16* __restrict__ BtH, u16* __restrict__ BtL, int K, int N, int k0, int n0,
    int t, float (*T)[65]) {
  const int r = t >> 4, c = (t & 15) * 4;
#pragma unroll
  for (int p = 0; p < 4; ++p) {
    float4 v = *(const float4*)&W[(size_t)(k0 + p * 16 + r) * N + n0 + c];
    T[p * 16 + r][c + 0] = v.x; T[p * 16 + r][c + 1] = v.y;
    T[p * 16 + r][c + 2] = v.z; T[p * 16 + r][c + 3] = v.w;
  }
  __syncthreads();
  const int rr = t >> 2, cc0 = (t & 3) * 16;
#pragma unroll
  for (int i4 = 0; i4 < 4; ++i4) {
    float f0 = T[cc0 + i4 * 4 + 0][rr];
    float f1 = T[cc0 + i4 * 4 + 1][rr];
    float f2 = T[cc0 + i4 * 4 + 2][rr];
    float f3 = T[cc0 + i4 * 4 + 3][rr];
    ushort4 h, l;
    h.x = f2bf(f0); l.x = f2bf(f0 - bf2f(h.x));
    h.y = f2bf(f1); l.y = f2bf(f1 - bf2f(h.y));
    h.z = f2bf(f2); l.z = f2bf(f2 - bf2f(h.z));
    h.w = f2bf(f3); l.w = f2bf(f3 - bf2f(h.w));
    size_t off = (size_t)(n0 + rr) * K + k0 + cc0 + i4 * 4;
    *(ushort4*)&BtH[off] = h;
    *(ushort4*)&BtL[off] = l;
  }
}

// ---------- fused prep: splitf(x) + split_T(Wq,Wk,Wv,Wo) + bias concat ------
__global__ __launch_bounds__(256) void prep(
    const float* __restrict__ x,  const float* __restrict__ Wq,
    const float* __restrict__ Wk, const float* __restrict__ Wv,
    const float* __restrict__ Wo, const float* __restrict__ bq,
    const float* __restrict__ bk, const float* __restrict__ bv,
    u16* __restrict__ xh, u16* __restrict__ xl,
    u16* __restrict__ WqkvH, u16* __restrict__ WqkvL,
    u16* __restrict__ WoH, u16* __restrict__ WoL, float* __restrict__ bcat) {
  __shared__ float T[64][65];
  const int bx = blockIdx.x, t = threadIdx.x;
  if (bx < 3072) {                       // splitf: 786432 float4s
    int i = bx * 256 + t;
    float4 v = ((const float4*)x)[i];
    ushort4 h, l;
    h.x = f2bf(v.x); l.x = f2bf(v.x - bf2f(h.x));
    h.y = f2bf(v.y); l.y = f2bf(v.y - bf2f(h.y));
    h.z = f2bf(v.z); l.z = f2bf(v.z - bf2f(h.z));
    h.w = f2bf(v.w); l.w = f2bf(v.w - bf2f(h.w));
    ((ushort4*)xh)[i] = h;
    ((ushort4*)xl)[i] = l;
  } else if (bx < 3648) {                // Wq: 24 n-tiles x 24 k-tiles
    int b = bx - 3072;
    split_T_tile(Wq, WqkvH, WqkvL, HID, HID, (b / 24) * 64, (b % 24) * 64, t, T);
  } else if (bx < 3744) {                // Wk: 4 x 24
    int b = bx - 3648;
    split_T_tile(Wk, WqkvH + (size_t)HID * HID, WqkvL + (size_t)HID * HID,
                 HID, 256, (b / 4) * 64, (b % 4) * 64, t, T);
  } else if (bx < 3840) {                // Wv: 4 x 24
    int b = bx - 3744;
    split_T_tile(Wv, WqkvH + (size_t)(HID + 256) * HID, WqkvL + (size_t)(HID + 256) * HID,
                 HID, 256, (b / 4) * 64, (b % 4) * 64, t, T);
  } else if (bx < 4416) {                // Wo: 24 x 24
    int b = bx - 3840;
    split_T_tile(Wo, WoH, WoL, HID, HID, (b / 24) * 64, (b % 24) * 64, t, T);
  } else {                               // bias concat: 8 blocks
    int i = (bx - 4416) * 256 + t;
    bcat[i] = (i < HID) ? bq[i] : (i < HID + 256 ? bk[i - HID] : bv[i - HID - 256]);
  }
}

// ------------- bf16x3 GEMM, 2-stage register pipeline (unchanged) -----------
#define G3_LOAD(ah, al, bh, bl, kk) do {                                      \
    _Pragma("unroll") for (int mt = 0; mt < 4; ++mt) {                        \
      size_t off = (size_t)(m0 + mt * 16 + l15) * K + (kk) + q8;              \
      ah[mt] = *(const bf16x8*)&Ah[off]; al[mt] = *(const bf16x8*)&Al[off]; } \
    _Pragma("unroll") for (int nt = 0; nt < 4; ++nt) {                        \
      size_t off = (size_t)(n0 + nt * 16 + l15) * K + (kk) + q8;              \
      bh[nt] = *(const bf16x8*)&Bh[off]; bl[nt] = *(const bf16x8*)&Bl[off]; } \
  } while (0)
#define G3_MFMA(ah, al, bh, bl) do {                                          \
    _Pragma("unroll") for (int mt = 0; mt < 4; ++mt)                          \
      _Pragma("unroll") for (int nt = 0; nt < 4; ++nt) {                      \
        acc[mt][nt] = __builtin_amdgcn_mfma_f32_16x16x32_bf16(ah[mt], bh[nt], acc[mt][nt], 0, 0, 0); \
        acc[mt][nt] = __builtin_amdgcn_mfma_f32_16x16x32_bf16(ah[mt], bl[nt], acc[mt][nt], 0, 0, 0); \
        acc[mt][nt] = __builtin_amdgcn_mfma_f32_16x16x32_bf16(al[mt], bh[nt], acc[mt][nt], 0, 0, 0); \
      }                                                                       \
  } while (0)

__global__ __launch_bounds__(64) void gemm3(
    const u16* __restrict__ Ah, const u16* __restrict__ Al,
    const u16* __restrict__ Bh, const u16* __restrict__ Bl,
    const float* __restrict__ bias, float* __restrict__ C,
    int K, int ldc) {
  const int m0 = blockIdx.y * 64, n0 = blockIdx.x * 64;
  const int lane = threadIdx.x, quad = lane >> 4, l15 = lane & 15;
  const int q8 = quad * 8;
  f32x4 acc[4][4];
#pragma unroll
  for (int mt = 0; mt < 4; ++mt)
#pragma unroll
    for (int nt = 0; nt < 4; ++nt) acc[mt][nt] = (f32x4){0.f, 0.f, 0.f, 0.f};
  bf16x8 ahA[4], alA[4], bhA[4], blA[4];
  bf16x8 ahB[4], alB[4], bhB[4], blB[4];
  G3_LOAD(ahA, alA, bhA, blA, 0);
  for (int k0 = 0; k0 < K; k0 += 64) {
    G3_LOAD(ahB, alB, bhB, blB, k0 + 32);
    G3_MFMA(ahA, alA, bhA, blA);
    if (k0 + 64 < K) G3_LOAD(ahA, alA, bhA, blA, k0 + 64);
    G3_MFMA(ahB, alB, bhB, blB);
  }
#pragma unroll
  for (int nt = 0; nt < 4; ++nt) {
    float bv = bias ? bias[n0 + nt * 16 + l15] : 0.f;
#pragma unroll
    for (int mt = 0; mt < 4; ++mt)
#pragma unroll
      for (int reg = 0; reg < 4; ++reg) {
        int row = m0 + mt * 16 + quad * 4 + reg;
        C[(size_t)row * ldc + n0 + nt * 16 + l15] = acc[mt][nt][reg] + bv;
      }
  }
}

// ---------- fused post: rope_q + build_k + build_vt -------------------------
__global__ __launch_bounds__(256) void post(
    const float* __restrict__ qkv, const float* __restrict__ k_hist,
    const float* __restrict__ v_hist, const float* __restrict__ cs,
    const float* __restrict__ sn, u16* __restrict__ Qb, u16* __restrict__ Kb,
    u16* __restrict__ Vt) {
  __shared__ u16 T[64][68];
  const int bx = blockIdx.x, t = threadIdx.x;
  if (bx < 1536) {                       // rope_q: NH*QL*16 float4-pairs
    int idx = bx * 256 + t;
    int dp4 = (idx & 15) * 4;
    int q   = (idx >> 4) & 2047;
    int h   = idx >> 15;
    const float* base = qkv + (size_t)q * NQKV + h * HD;
    float4 x1 = *(const float4*)&base[dp4];
    float4 x2 = *(const float4*)&base[dp4 + 64];
    float4 c = *(const float4*)&cs[q * 64 + dp4];
    float4 s = *(const float4*)&sn[q * 64 + dp4];
    u16* ob = Qb + ((size_t)h * QL + q) * HD;
    ushort4 o1, o2;
    o1.x = f2bf((x1.x * c.x - x2.x * s.x) * QSCALE);
    o1.y = f2bf((x1.y * c.y - x2.y * s.y) * QSCALE);
    o1.z = f2bf((x1.z * c.z - x2.z * s.z) * QSCALE);
    o1.w = f2bf((x1.w * c.w - x2.w * s.w) * QSCALE);
    o2.x = f2bf((x1.x * s.x + x2.x * c.x) * QSCALE);
    o2.y = f2bf((x1.y * s.y + x2.y * c.y) * QSCALE);
    o2.z = f2bf((x1.z * s.z + x2.z * c.z) * QSCALE);
    o2.w = f2bf((x1.w * s.w + x2.w * c.w) * QSCALE);
    *(ushort4*)&ob[dp4]      = o1;
    *(ushort4*)&ob[dp4 + 64] = o2;
  } else if (bx < 2048) {                // build_k: NKVH*KLEN*16
    int idx = (bx - 1536) * 256 + t;
    int dp4 = (idx & 15) * 4;
    int tt  = (idx >> 4) & 4095;
    int kvh = idx >> 16;
    u16* ob = Kb + ((size_t)kvh * KLEN + tt) * HD;
    if (tt < HISTN) {
      const float* hb = k_hist + ((size_t)tt * NKVH + kvh) * HD;
      float4 a = *(const float4*)&hb[dp4];
      float4 b = *(const float4*)&hb[dp4 + 64];
      ushort4 o1, o2;
      o1.x = f2bf(a.x); o1.y = f2bf(a.y); o1.z = f2bf(a.z); o1.w = f2bf(a.w);
      o2.x = f2bf(b.x); o2.y = f2bf(b.y); o2.z = f2bf(b.z); o2.w = f2bf(b.w);
      *(ushort4*)&ob[dp4]      = o1;
      *(ushort4*)&ob[dp4 + 64] = o2;
    } else {
      int q = tt - HISTN;
      const float* base = qkv + (size_t)q * NQKV + HID + kvh * HD;
      float4 x1 = *(const float4*)&base[dp4];
      float4 x2 = *(const float4*)&base[dp4 + 64];
      float4 c = *(const float4*)&cs[q * 64 + dp4];
      float4 s = *(const float4*)&sn[q * 64 + dp4];
      ushort4 o1, o2;
      o1.x = f2bf(x1.x * c.x - x2.x * s.x);
      o1.y = f2bf(x1.y * c.y - x2.y * s.y);
      o1.z = f2bf(x1.z * c.z - x2.z * s.z);
      o1.w = f2bf(x1.w * c.w - x2.w * s.w);
      o2.x = f2bf(x1.x * s.x + x2.x * c.x);
      o2.y = f2bf(x1.y * s.y + x2.y * c.y);
      o2.z = f2bf(x1.z * s.z + x2.z * c.z);
      o2.w = f2bf(x1.w * s.w + x2.w * c.w);
      *(ushort4*)&ob[dp4]      = o1;
      *(ushort4*)&ob[dp4 + 64] = o2;
    }
  } else {                               // build_vt: 260 blocks
    int b = bx - 2048;
    int xt = b % 65, rest = b / 65;
    int dh = rest & 1, kvh = rest >> 1;
    if (xt == 64) {                      // rows 128..143: 128=ones, rest zero
      int r0 = 128 + dh * 8;
      u16* base = Vt + ((size_t)kvh * VTROWS) * KLEN;
      for (int i = t; i < 8192; i += 256) {
        int row = r0 + (i >> 10), c4 = (i & 1023) * 4;
        u16 v = (row == 128) ? (u16)0x3F80 : (u16)0;
        ushort4 o4 = {v, v, v, v};
        *(ushort4*)&base[(size_t)row * KLEN + c4] = o4;
      }
      return;
    }
    const int t0 = xt * 64, d0 = dh * 64;
    const int r = t >> 4, c = (t & 15) * 4;
#pragma unroll
    for (int p = 0; p < 4; ++p) {
      int tt = t0 + p * 16 + r;
      float4 v;
      if (tt < HISTN) v = *(const float4*)&v_hist[((size_t)tt * NKVH + kvh) * HD + d0 + c];
      else            v = *(const float4*)&qkv[(size_t)(tt - HISTN) * NQKV + HID + 256 + kvh * HD + d0 + c];
      T[p * 16 + r][c + 0] = f2bf(v.x); T[p * 16 + r][c + 1] = f2bf(v.y);
      T[p * 16 + r][c + 2] = f2bf(v.z); T[p * 16 + r][c + 3] = f2bf(v.w);
    }
    __syncthreads();
    const int dr = t >> 2, cc0 = (t & 3) * 16;
#pragma unroll
    for (int i4 = 0; i4 < 4; ++i4) {
      ushort4 o4;
      o4.x = T[cc0 + i4 * 4 + 0][dr];
      o4.y = T[cc0 + i4 * 4 + 1][dr];
      o4.z = T[cc0 + i4 * 4 + 2][dr];
      o4.w = T[cc0 + i4 * 4 + 3][dr];
      *(ushort4*)&Vt[((size_t)kvh * VTROWS + d0 + dr) * KLEN + t0 + cc0 + i4 * 4] = o4;
    }
  }
}

// -------- flash attention v4: batched loads, __launch_bounds__(512,2) -------
// Root-cause fix for R6's latency serialization: all 16 K-frag loads hoisted
// into bK[16] (one latency exposure), V loads issued in 2x9 batches early so
// their latency hides under QK-MFMA + exp/pack VALU. Peak live regs ~240.
#define MWRITE(buf) do {                                                      \
    _Pragma("unroll") for (int mt = 0; mt < 2; ++mt)                          \
      _Pragma("unroll") for (int reg = 0; reg < 4; ++reg) {                   \
        int r = mt * 16 + quad * 4 + reg;                                     \
        if (l15 == 0) cL[(buf) * 32 + r] = ol[mt][reg];                       \
        _Pragma("unroll") for (int dt = 0; dt < 8; ++dt)                      \
          cO[((buf) * 32 + r) * 132 + dt * 16 + l15] = o[mt][dt][reg];        \
      }                                                                       \
  } while (0)
#define MMERGE(buf) do {                                                      \
    _Pragma("unroll") for (int mt = 0; mt < 2; ++mt)                          \
      _Pragma("unroll") for (int reg = 0; reg < 4; ++reg) {                   \
        int r = mt * 16 + quad * 4 + reg;                                     \
        if (l15 == 0) ol[mt][reg] += cL[(buf) * 32 + r];                      \
        _Pragma("unroll") for (int dt = 0; dt < 8; ++dt)                      \
          o[mt][dt][reg] += cO[((buf) * 32 + r) * 132 + dt * 16 + l15];       \
      }                                                                       \
  } while (0)

__global__ __launch_bounds__(512, 2) void attn4(
    const u16* __restrict__ Q, const u16* __restrict__ K,
    const u16* __restrict__ Vt, u16* __restrict__ OH, u16* __restrict__ OL) {
  __shared__ __align__(16) char smem[36864];
  u16* sP = (u16*)smem;
  const int h = blockIdx.y;
  const int bx = blockIdx.x;
  const int qt = (bx & 1) ? (63 - (bx >> 1)) : (bx >> 1);  // long/short pairing
  const int q0 = qt * 32, kvh = h / 6;
  const int t = threadIdx.x, lane = t & 63, w = t >> 6;    // w in 0..7
  const int quad = lane >> 4, l15 = lane & 15, q8 = quad * 8;

  const u16* Qg = Q + ((size_t)h * QL + q0) * HD;
  bf16x8 Qf[2][4];
#pragma unroll
  for (int mt = 0; mt < 2; ++mt)
#pragma unroll
    for (int dc = 0; dc < 4; ++dc)
      Qf[mt][dc] = *(const bf16x8*)&Qg[(mt * 16 + l15) * HD + dc * 32 + q8];

  const int nsteps = (q0 + 32 + HISTN + 63) >> 6;
  const int bas = nsteps >> 3, rem = nsteps & 7;
  const int cnt = bas + (w < rem ? 1 : 0);
  const int s0  = w * bas + (w < rem ? w : rem);

  f32x4 o[2][8], ol[2];
#pragma unroll
  for (int mt = 0; mt < 2; ++mt) {
    ol[mt] = (f32x4){0.f, 0.f, 0.f, 0.f};
#pragma unroll
    for (int dt = 0; dt < 8; ++dt) o[mt][dt] = (f32x4){0.f, 0.f, 0.f, 0.f};
  }

  const u16* Kh = K + (size_t)kvh * KLEN * HD;
  const u16* Vh = Vt + (size_t)kvh * VTROWS * KLEN;
  u16* sPw = sP + w * 2304;   // single 32x72 u16 patch per wave

  for (int s = s0; s < s0 + cnt; ++s) {
    const int k0 = s << 6;
    // ---- batch ALL K-fragment loads (one latency exposure) ----
    bf16x8 bK[16];
#pragma unroll
    for (int dc = 0; dc < 4; ++dc)
#pragma unroll
      for (int kt = 0; kt < 4; ++kt)
        bK[dc * 4 + kt] = *(const bf16x8*)&Kh[(size_t)(k0 + kt * 16 + l15) * HD + dc * 32 + q8];
    // ---- issue first V batch early: latency hides under QK + exp ----
    bf16x8 bV0[9];
#pragma unroll
    for (int dt = 0; dt < 9; ++dt)
      bV0[dt] = *(const bf16x8*)&Vh[(size_t)(dt * 16 + l15) * KLEN + k0 + q8];
    // ---- QK ----
    f32x4 sc[2][4];
#pragma unroll
    for (int mt = 0; mt < 2; ++mt)
#pragma unroll
      for (int kt = 0; kt < 4; ++kt) sc[mt][kt] = (f32x4){0.f, 0.f, 0.f, 0.f};
#pragma unroll
    for (int dc = 0; dc < 4; ++dc)
#pragma unroll
      for (int mt = 0; mt < 2; ++mt)
#pragma unroll
        for (int kt = 0; kt < 4; ++kt)
          sc[mt][kt] = __builtin_amdgcn_mfma_f32_16x16x32_bf16(Qf[mt][dc], bK[dc * 4 + kt], sc[mt][kt], 0, 0, 0);
    if (k0 + 63 - HISTN > q0) {   // causal boundary inside this step
#pragma unroll
      for (int mt = 0; mt < 2; ++mt)
#pragma unroll
        for (int kt = 0; kt < 4; ++kt) {
          int kg = k0 + kt * 16 + l15;
#pragma unroll
          for (int reg = 0; reg < 4; ++reg)
            if (kg > q0 + mt * 16 + quad * 4 + reg + HISTN) sc[mt][kt][reg] = -INFINITY;
        }
    }
    // ---- exp + pack P to LDS (VALU; overlaps bV0 latency) ----
#pragma unroll
    for (int mt = 0; mt < 2; ++mt)
#pragma unroll
      for (int reg = 0; reg < 4; ++reg)
#pragma unroll
        for (int kt = 0; kt < 4; ++kt) {
          float p = __expf(sc[mt][kt][reg]);
          sPw[(mt * 16 + quad * 4 + reg) * 72 + kt * 16 + l15] = f2bf(p);
        }
    // ---- issue second V batch ----
    bf16x8 bV1[9];
#pragma unroll
    for (int dt = 0; dt < 9; ++dt)
      bV1[dt] = *(const bf16x8*)&Vh[(size_t)(dt * 16 + l15) * KLEN + k0 + 32 + q8];
    // ---- PV kc=0 ----
    {
      bf16x8 aP[2];
#pragma unroll
      for (int mt = 0; mt < 2; ++mt)
        aP[mt] = *(const bf16x8*)&sPw[(mt * 16 + l15) * 72 + q8];
#pragma unroll
      for (int dt = 0; dt < 8; ++dt)
#pragma unroll
        for (int mt = 0; mt < 2; ++mt)
          o[mt][dt] = __builtin_amdgcn_mfma_f32_16x16x32_bf16(aP[mt], bV0[dt], o[mt][dt], 0, 0, 0);
#pragma unroll
      for (int mt = 0; mt < 2; ++mt)
        ol[mt] = __builtin_amdgcn_mfma_f32_16x16x32_bf16(aP[mt], bV0[8], ol[mt], 0, 0, 0);
    }
    // ---- PV kc=1 ----
    {
      bf16x8 aP[2];
#pragma unroll
      for (int mt = 0; mt < 2; ++mt)
        aP[mt] = *(const bf16x8*)&sPw[(mt * 16 + l15) * 72 + 32 + q8];
#pragma unroll
      for (int dt = 0; dt < 8; ++dt)
#pragma unroll
        for (int mt = 0; mt < 2; ++mt)
          o[mt][dt] = __builtin_amdgcn_mfma_f32_16x16x32_bf16(aP[mt], bV1[dt], o[mt][dt], 0, 0, 0);
#pragma unroll
      for (int mt = 0; mt < 2; ++mt)
        ol[mt] = __builtin_amdgcn_mfma_f32_16x16x32_bf16(aP[mt], bV1[8], ol[mt], 0, 0, 0);
    }
  }

  // ---- 8-wave merge: plain sums through 2 LDS buffers ----
  __syncthreads();                       // sP dead; alias combine buffers
  float* cO   = (float*)smem;            // [2][32][132]
  float* cL   = (float*)(smem + 33792);  // [2][32]
  float* cInv = (float*)(smem + 34048);  // [32]
  if (w == 1) MWRITE(0);
  if (w == 3) MWRITE(1);
  __syncthreads();
  if (w == 0) MMERGE(0);
  if (w == 2) MMERGE(1);
  __syncthreads();
  if (w == 5) MWRITE(0);
  if (w == 7) MWRITE(1);
  __syncthreads();
  if (w == 4) MMERGE(0);
  if (w == 6) MMERGE(1);
  __syncthreads();
  if (w == 2) MWRITE(0);
  if (w == 6) MWRITE(1);
  __syncthreads();
  if (w == 0) MMERGE(0);
  if (w == 4) MMERGE(1);
  __syncthreads();
  if (w == 4) MWRITE(0);
  __syncthreads();
  if (w == 0) {
    MMERGE(0);
#pragma unroll
    for (int mt = 0; mt < 2; ++mt)
#pragma unroll
      for (int reg = 0; reg < 4; ++reg) {
        int r = mt * 16 + quad * 4 + reg;
        if (l15 == 0) cInv[r] = 1.f / ol[mt][reg];
      }
#pragma unroll
    for (int mt = 0; mt < 2; ++mt)
#pragma unroll
      for (int reg = 0; reg < 4; ++reg) {
        int r = mt * 16 + quad * 4 + reg;
        float inv = cInv[r];
        int row = q0 + r;
#pragma unroll
        for (int dt = 0; dt < 8; ++dt) {
          float val = o[mt][dt][reg] * inv;
          u16 hv = f2bf(val);
          size_t oi = (size_t)row * HID + h * HD + dt * 16 + l15;
          OH[oi] = hv;
          OL[oi] = f2bf(val - bf2f(hv));
        }
      }
  }
}

extern "C" void kernel_launch(void* const* d_in, const int* in_sizes, int n_in,
                              void* d_out, int out_size, void* d_ws, size_t ws_size,
                              hipStream_t stream) {
  (void)in_sizes; (void)n_in; (void)out_size; (void)ws_size;
  const float* x      = (const float*)d_in[0];
  const float* Wq     = (const float*)d_in[1];
  const float* bq     = (const float*)d_in[2];
  const float* Wk     = (const float*)d_in[3];
  const float* bk     = (const float*)d_in[4];
  const float* Wv     = (const float*)d_in[5];
  const float* bv     = (const float*)d_in[6];
  const float* Wo     = (const float*)d_in[7];
  const float* k_hist = (const float*)d_in[8];
  const float* v_hist = (const float*)d_in[9];
  const float* fcos   = (const float*)d_in[10];
  const float* fsin   = (const float*)d_in[11];
  float* out = (float*)d_out;

  char* p = (char*)d_ws;
  float* qkv   = (float*)p;  p += (size_t)QL * NQKV * 4;
  u16*   Qb    = (u16*)p;    p += (size_t)NH * QL * HD * 2;
  u16*   Kb    = (u16*)p;    p += (size_t)NKVH * KLEN * HD * 2;
  u16*   Vtb   = (u16*)p;    p += (size_t)NKVH * VTROWS * KLEN * 2;
  u16*   xh    = (u16*)p;    p += (size_t)QL * HID * 2;             // alias attnH
  u16*   xl    = (u16*)p;    p += (size_t)QL * HID * 2;             // alias attnL
  u16*   WqkvH = (u16*)p;    p += (size_t)NQKV * HID * 2;
  u16*   WqkvL = (u16*)p;    p += (size_t)NQKV * HID * 2;
  u16*   WoH   = (u16*)p;    p += (size_t)HID * HID * 2;
  u16*   WoL   = (u16*)p;    p += (size_t)HID * HID * 2;
  float* bcat  = (float*)p;  p += (size_t)NQKV * 4;                 // ~64 MB total
  u16* attnH = xh;  u16* attnL = xl;    // x dead after QKV gemm

  prep<<<4424, 256, 0, stream>>>(x, Wq, Wk, Wv, Wo, bq, bk, bv,
                                 xh, xl, WqkvH, WqkvL, WoH, WoL, bcat);
  gemm3<<<dim3(32, 32), 64, 0, stream>>>(xh, xl, WqkvH, WqkvL, bcat, qkv, HID, NQKV);
  post<<<2308, 256, 0, stream>>>(qkv, k_hist, v_hist, fcos, fsin, Qb, Kb, Vtb);
  attn4<<<dim3(64, 12), 512, 0, stream>>>(Qb, Kb, Vtb, attnH, attnL);
  gemm3<<<dim3(24, 32), 64, 0, stream>>>(attnH, attnL, WoH, WoL, nullptr, out, HID, HID);
}

// Round 8
// 437.108 us; speedup vs baseline: 4.4014x; 1.1529x over previous
//
#include <hip/hip_runtime.h>
#include <math.h>

#define QL 2048
#define HISTN 2048
#define KLEN 4096
#define NH 12
#define NKVH 2
#define HD 128
#define HID 1536
#define NQKV 2048   // 1536 q + 256 k + 256 v
#define VTROWS 144  // 128 d + 1 ones + 15 zeros (ones now unused by attn)
#define QSCALE 0.08838834764831845f  // 1/sqrt(128)

typedef unsigned short u16;
typedef short bf16x8 __attribute__((ext_vector_type(8)));
typedef float f32x4 __attribute__((ext_vector_type(4)));

__device__ __forceinline__ u16 f2bf(float f) {
  union { float f; unsigned u; } v; v.f = f;
  unsigned r = v.u + 0x7FFFu + ((v.u >> 16) & 1u);
  return (u16)(r >> 16);
}
__device__ __forceinline__ float bf2f(u16 h) {
  union { unsigned u; float f; } v; v.u = ((unsigned)h) << 16; return v.f;
}

// ---------- split_T tile helper: W[K][N] 64x64 tile -> Bt[N][K] hi/lo -------
__device__ __forceinline__ void split_T_tile(const float* __restrict__ W,
    u16* __restrict__ BtH, u16* __restrict__ BtL, int K, int N, int k0, int n0,
    int t, float (*T)[65]) {
  const int r = t >> 4, c = (t & 15) * 4;
#pragma unroll
  for (int p = 0; p < 4; ++p) {
    float4 v = *(const float4*)&W[(size_t)(k0 + p * 16 + r) * N + n0 + c];
    T[p * 16 + r][c + 0] = v.x; T[p * 16 + r][c + 1] = v.y;
    T[p * 16 + r][c + 2] = v.z; T[p * 16 + r][c + 3] = v.w;
  }
  __syncthreads();
  const int rr = t >> 2, cc0 = (t & 3) * 16;
#pragma unroll
  for (int i4 = 0; i4 < 4; ++i4) {
    float f0 = T[cc0 + i4 * 4 + 0][rr];
    float f1 = T[cc0 + i4 * 4 + 1][rr];
    float f2 = T[cc0 + i4 * 4 + 2][rr];
    float f3 = T[cc0 + i4 * 4 + 3][rr];
    ushort4 h, l;
    h.x = f2bf(f0); l.x = f2bf(f0 - bf2f(h.x));
    h.y = f2bf(f1); l.y = f2bf(f1 - bf2f(h.y));
    h.z = f2bf(f2); l.z = f2bf(f2 - bf2f(h.z));
    h.w = f2bf(f3); l.w = f2bf(f3 - bf2f(h.w));
    size_t off = (size_t)(n0 + rr) * K + k0 + cc0 + i4 * 4;
    *(ushort4*)&BtH[off] = h;
    *(ushort4*)&BtL[off] = l;
  }
}

// ---------- fused prep: splitf(x) + split_T(Wq,Wk,Wv,Wo) + bias concat ------
__global__ __launch_bounds__(256) void prep(
    const float* __restrict__ x,  const float* __restrict__ Wq,
    const float* __restrict__ Wk, const float* __restrict__ Wv,
    const float* __restrict__ Wo, const float* __restrict__ bq,
    const float* __restrict__ bk, const float* __restrict__ bv,
    u16* __restrict__ xh, u16* __restrict__ xl,
    u16* __restrict__ WqkvH, u16* __restrict__ WqkvL,
    u16* __restrict__ WoH, u16* __restrict__ WoL, float* __restrict__ bcat) {
  __shared__ float T[64][65];
  const int bx = blockIdx.x, t = threadIdx.x;
  if (bx < 3072) {                       // splitf: 786432 float4s
    int i = bx * 256 + t;
    float4 v = ((const float4*)x)[i];
    ushort4 h, l;
    h.x = f2bf(v.x); l.x = f2bf(v.x - bf2f(h.x));
    h.y = f2bf(v.y); l.y = f2bf(v.y - bf2f(h.y));
    h.z = f2bf(v.z); l.z = f2bf(v.z - bf2f(h.z));
    h.w = f2bf(v.w); l.w = f2bf(v.w - bf2f(h.w));
    ((ushort4*)xh)[i] = h;
    ((ushort4*)xl)[i] = l;
  } else if (bx < 3648) {                // Wq: 24 n-tiles x 24 k-tiles
    int b = bx - 3072;
    split_T_tile(Wq, WqkvH, WqkvL, HID, HID, (b / 24) * 64, (b % 24) * 64, t, T);
  } else if (bx < 3744) {                // Wk: 4 x 24
    int b = bx - 3648;
    split_T_tile(Wk, WqkvH + (size_t)HID * HID, WqkvL + (size_t)HID * HID,
                 HID, 256, (b / 4) * 64, (b % 4) * 64, t, T);
  } else if (bx < 3840) {                // Wv: 4 x 24
    int b = bx - 3744;
    split_T_tile(Wv, WqkvH + (size_t)(HID + 256) * HID, WqkvL + (size_t)(HID + 256) * HID,
                 HID, 256, (b / 4) * 64, (b % 4) * 64, t, T);
  } else if (bx < 4416) {                // Wo: 24 x 24
    int b = bx - 3840;
    split_T_tile(Wo, WoH, WoL, HID, HID, (b / 24) * 64, (b % 24) * 64, t, T);
  } else {                               // bias concat: 8 blocks
    int i = (bx - 4416) * 256 + t;
    bcat[i] = (i < HID) ? bq[i] : (i < HID + 256 ? bk[i - HID] : bv[i - HID - 256]);
  }
}

// ------------- bf16x3 GEMM, 2-stage register pipeline (unchanged) -----------
#define G3_LOAD(ah, al, bh, bl, kk) do {                                      \
    _Pragma("unroll") for (int mt = 0; mt < 4; ++mt) {                        \
      size_t off = (size_t)(m0 + mt * 16 + l15) * K + (kk) + q8;              \
      ah[mt] = *(const bf16x8*)&Ah[off]; al[mt] = *(const bf16x8*)&Al[off]; } \
    _Pragma("unroll") for (int nt = 0; nt < 4; ++nt) {                        \
      size_t off = (size_t)(n0 + nt * 16 + l15) * K + (kk) + q8;              \
      bh[nt] = *(const bf16x8*)&Bh[off]; bl[nt] = *(const bf16x8*)&Bl[off]; } \
  } while (0)
#define G3_MFMA(ah, al, bh, bl) do {                                          \
    _Pragma("unroll") for (int mt = 0; mt < 4; ++mt)                          \
      _Pragma("unroll") for (int nt = 0; nt < 4; ++nt) {                      \
        acc[mt][nt] = __builtin_amdgcn_mfma_f32_16x16x32_bf16(ah[mt], bh[nt], acc[mt][nt], 0, 0, 0); \
        acc[mt][nt] = __builtin_amdgcn_mfma_f32_16x16x32_bf16(ah[mt], bl[nt], acc[mt][nt], 0, 0, 0); \
        acc[mt][nt] = __builtin_amdgcn_mfma_f32_16x16x32_bf16(al[mt], bh[nt], acc[mt][nt], 0, 0, 0); \
      }                                                                       \
  } while (0)

__global__ __launch_bounds__(64) void gemm3(
    const u16* __restrict__ Ah, const u16* __restrict__ Al,
    const u16* __restrict__ Bh, const u16* __restrict__ Bl,
    const float* __restrict__ bias, float* __restrict__ C,
    int K, int ldc) {
  const int m0 = blockIdx.y * 64, n0 = blockIdx.x * 64;
  const int lane = threadIdx.x, quad = lane >> 4, l15 = lane & 15;
  const int q8 = quad * 8;
  f32x4 acc[4][4];
#pragma unroll
  for (int mt = 0; mt < 4; ++mt)
#pragma unroll
    for (int nt = 0; nt < 4; ++nt) acc[mt][nt] = (f32x4){0.f, 0.f, 0.f, 0.f};
  bf16x8 ahA[4], alA[4], bhA[4], blA[4];
  bf16x8 ahB[4], alB[4], bhB[4], blB[4];
  G3_LOAD(ahA, alA, bhA, blA, 0);
  for (int k0 = 0; k0 < K; k0 += 64) {
    G3_LOAD(ahB, alB, bhB, blB, k0 + 32);
    G3_MFMA(ahA, alA, bhA, blA);
    if (k0 + 64 < K) G3_LOAD(ahA, alA, bhA, blA, k0 + 64);
    G3_MFMA(ahB, alB, bhB, blB);
  }
#pragma unroll
  for (int nt = 0; nt < 4; ++nt) {
    float bv = bias ? bias[n0 + nt * 16 + l15] : 0.f;
#pragma unroll
    for (int mt = 0; mt < 4; ++mt)
#pragma unroll
      for (int reg = 0; reg < 4; ++reg) {
        int row = m0 + mt * 16 + quad * 4 + reg;
        C[(size_t)row * ldc + n0 + nt * 16 + l15] = acc[mt][nt][reg] + bv;
      }
  }
}

// ---------- fused post: rope_q + build_k + build_vt -------------------------
__global__ __launch_bounds__(256) void post(
    const float* __restrict__ qkv, const float* __restrict__ k_hist,
    const float* __restrict__ v_hist, const float* __restrict__ cs,
    const float* __restrict__ sn, u16* __restrict__ Qb, u16* __restrict__ Kb,
    u16* __restrict__ Vt) {
  __shared__ u16 T[64][68];
  const int bx = blockIdx.x, t = threadIdx.x;
  if (bx < 1536) {                       // rope_q: NH*QL*16 float4-pairs
    int idx = bx * 256 + t;
    int dp4 = (idx & 15) * 4;
    int q   = (idx >> 4) & 2047;
    int h   = idx >> 15;
    const float* base = qkv + (size_t)q * NQKV + h * HD;
    float4 x1 = *(const float4*)&base[dp4];
    float4 x2 = *(const float4*)&base[dp4 + 64];
    float4 c = *(const float4*)&cs[q * 64 + dp4];
    float4 s = *(const float4*)&sn[q * 64 + dp4];
    u16* ob = Qb + ((size_t)h * QL + q) * HD;
    ushort4 o1, o2;
    o1.x = f2bf((x1.x * c.x - x2.x * s.x) * QSCALE);
    o1.y = f2bf((x1.y * c.y - x2.y * s.y) * QSCALE);
    o1.z = f2bf((x1.z * c.z - x2.z * s.z) * QSCALE);
    o1.w = f2bf((x1.w * c.w - x2.w * s.w) * QSCALE);
    o2.x = f2bf((x1.x * s.x + x2.x * c.x) * QSCALE);
    o2.y = f2bf((x1.y * s.y + x2.y * c.y) * QSCALE);
    o2.z = f2bf((x1.z * s.z + x2.z * c.z) * QSCALE);
    o2.w = f2bf((x1.w * s.w + x2.w * c.w) * QSCALE);
    *(ushort4*)&ob[dp4]      = o1;
    *(ushort4*)&ob[dp4 + 64] = o2;
  } else if (bx < 2048) {                // build_k: NKVH*KLEN*16
    int idx = (bx - 1536) * 256 + t;
    int dp4 = (idx & 15) * 4;
    int tt  = (idx >> 4) & 4095;
    int kvh = idx >> 16;
    u16* ob = Kb + ((size_t)kvh * KLEN + tt) * HD;
    if (tt < HISTN) {
      const float* hb = k_hist + ((size_t)tt * NKVH + kvh) * HD;
      float4 a = *(const float4*)&hb[dp4];
      float4 b = *(const float4*)&hb[dp4 + 64];
      ushort4 o1, o2;
      o1.x = f2bf(a.x); o1.y = f2bf(a.y); o1.z = f2bf(a.z); o1.w = f2bf(a.w);
      o2.x = f2bf(b.x); o2.y = f2bf(b.y); o2.z = f2bf(b.z); o2.w = f2bf(b.w);
      *(ushort4*)&ob[dp4]      = o1;
      *(ushort4*)&ob[dp4 + 64] = o2;
    } else {
      int q = tt - HISTN;
      const float* base = qkv + (size_t)q * NQKV + HID + kvh * HD;
      float4 x1 = *(const float4*)&base[dp4];
      float4 x2 = *(const float4*)&base[dp4 + 64];
      float4 c = *(const float4*)&cs[q * 64 + dp4];
      float4 s = *(const float4*)&sn[q * 64 + dp4];
      ushort4 o1, o2;
      o1.x = f2bf(x1.x * c.x - x2.x * s.x);
      o1.y = f2bf(x1.y * c.y - x2.y * s.y);
      o1.z = f2bf(x1.z * c.z - x2.z * s.z);
      o1.w = f2bf(x1.w * c.w - x2.w * s.w);
      o2.x = f2bf(x1.x * s.x + x2.x * c.x);
      o2.y = f2bf(x1.y * s.y + x2.y * c.y);
      o2.z = f2bf(x1.z * s.z + x2.z * c.z);
      o2.w = f2bf(x1.w * s.w + x2.w * c.w);
      *(ushort4*)&ob[dp4]      = o1;
      *(ushort4*)&ob[dp4 + 64] = o2;
    }
  } else {                               // build_vt: 260 blocks
    int b = bx - 2048;
    int xt = b % 65, rest = b / 65;
    int dh = rest & 1, kvh = rest >> 1;
    if (xt == 64) {                      // rows 128..143: 128=ones, rest zero
      int r0 = 128 + dh * 8;
      u16* base = Vt + ((size_t)kvh * VTROWS) * KLEN;
      for (int i = t; i < 8192; i += 256) {
        int row = r0 + (i >> 10), c4 = (i & 1023) * 4;
        u16 v = (row == 128) ? (u16)0x3F80 : (u16)0;
        ushort4 o4 = {v, v, v, v};
        *(ushort4*)&base[(size_t)row * KLEN + c4] = o4;
      }
      return;
    }
    const int t0 = xt * 64, d0 = dh * 64;
    const int r = t >> 4, c = (t & 15) * 4;
#pragma unroll
    for (int p = 0; p < 4; ++p) {
      int tt = t0 + p * 16 + r;
      float4 v;
      if (tt < HISTN) v = *(const float4*)&v_hist[((size_t)tt * NKVH + kvh) * HD + d0 + c];
      else            v = *(const float4*)&qkv[(size_t)(tt - HISTN) * NQKV + HID + 256 + kvh * HD + d0 + c];
      T[p * 16 + r][c + 0] = f2bf(v.x); T[p * 16 + r][c + 1] = f2bf(v.y);
      T[p * 16 + r][c + 2] = f2bf(v.z); T[p * 16 + r][c + 3] = f2bf(v.w);
    }
    __syncthreads();
    const int dr = t >> 2, cc0 = (t & 3) * 16;
#pragma unroll
    for (int i4 = 0; i4 < 4; ++i4) {
      ushort4 o4;
      o4.x = T[cc0 + i4 * 4 + 0][dr];
      o4.y = T[cc0 + i4 * 4 + 1][dr];
      o4.z = T[cc0 + i4 * 4 + 2][dr];
      o4.w = T[cc0 + i4 * 4 + 3][dr];
      *(ushort4*)&Vt[((size_t)kvh * VTROWS + d0 + dr) * KLEN + t0 + cc0 + i4 * 4] = o4;
    }
  }
}

// -------- attn6: LDS-staged tiles shared by 6 heads (wave = head) -----------
// Block = 384 thr / 6 waves, one kvh, 32 q-rows, 1/4 of the key range.
// K/V tiles staged once per step via global_load_lds (coalesced, source-XOR-
// swizzled so ds_read_b128 frag reads are bank-conflict-free). Partial (o,l)
// accumulated to global fp32 via device-scope atomics; attn_norm finalizes.
__global__ __launch_bounds__(384, 3) void attn6(
    const u16* __restrict__ Q, const u16* __restrict__ K,
    const u16* __restrict__ Vt, float* __restrict__ oacc) {
  __shared__ __align__(16) u16 sK[64 * 128];   // 16 KB, swizzled
  __shared__ __align__(16) u16 sV[128 * 64];   // 16 KB, swizzled (rows=d)
  __shared__ __align__(16) u16 sP[6][2304];    // per-wave 32x72 P patch
  const int kvh = blockIdx.y;
  const int qt = blockIdx.x >> 2, slice = blockIdx.x & 3;
  const int q0 = qt * 32;
  const int t = threadIdx.x, lane = t & 63, w = t / 64;   // w = head-in-group
  const int h = kvh * 6 + w;
  const int quad = lane >> 4, l15 = lane & 15, q8 = quad * 8;

  // Q fragments (once per block; scattered loads acceptable here)
  const u16* Qg = Q + ((size_t)h * QL + q0) * HD;
  bf16x8 Qf[2][4];
#pragma unroll
  for (int mt = 0; mt < 2; ++mt)
#pragma unroll
    for (int dc = 0; dc < 4; ++dc)
      Qf[mt][dc] = *(const bf16x8*)&Qg[(mt * 16 + l15) * HD + dc * 32 + q8];

  const int nsteps = (q0 + 32 + HISTN + 63) >> 6;
  const int bas = nsteps >> 2, rem = nsteps & 3;
  const int cnt = bas + (slice < rem ? 1 : 0);
  const int s0  = slice * bas + (slice < rem ? slice : rem);

  f32x4 o[2][8], ol[2];
#pragma unroll
  for (int mt = 0; mt < 2; ++mt) {
    ol[mt] = (f32x4){0.f, 0.f, 0.f, 0.f};
#pragma unroll
    for (int dt = 0; dt < 8; ++dt) o[mt][dt] = (f32x4){0.f, 0.f, 0.f, 0.f};
  }

  // constant B-frag for the ones-row (l accumulation): col 0 = 1.0
  bf16x8 onesf;
  {
    short v = (l15 == 0) ? (short)0x3F80 : (short)0;
#pragma unroll
    for (int j = 0; j < 8; ++j) onesf[j] = v;
  }

  const u16* Kh = K + (size_t)kvh * KLEN * HD;
  const u16* Vh = Vt + (size_t)kvh * VTROWS * KLEN;
  u16* sPw = sP[w];
  const int x7 = l15 & 7;

  for (int s = s0; s < s0 + cnt; ++s) {
    const int k0 = s << 6;
    __syncthreads();   // all waves done reading previous tiles
    // ---- stage K (16 instrs) + V (16 instrs), split across 6 waves ----
    for (int i = w; i < 32; i += 6) {
      if (i < 16) {
        int r = 4 * i + (lane >> 4);        // K row 0..63
        int c = lane & 15;                  // 16B chunk 0..15
        const u16* src = Kh + (size_t)(k0 + r) * HD + ((c ^ (r & 7)) << 3);
        __builtin_amdgcn_global_load_lds(
            (const __attribute__((address_space(1))) void*)src,
            (__attribute__((address_space(3))) void*)&sK[i * 512], 16, 0, 0);
      } else {
        int j = i - 16;
        int r = 8 * j + (lane >> 3);        // V d-row 0..127
        int c = lane & 7;                   // 16B chunk 0..7
        const u16* src = Vh + (size_t)r * KLEN + k0 + ((c ^ (r & 7)) << 3);
        __builtin_amdgcn_global_load_lds(
            (const __attribute__((address_space(1))) void*)src,
            (__attribute__((address_space(3))) void*)&sV[j * 512], 16, 0, 0);
      }
    }
    __syncthreads();   // compiler drains vmcnt before barrier: tiles ready
    // ---- QK ----
    f32x4 sc[2][4];
#pragma unroll
    for (int mt = 0; mt < 2; ++mt)
#pragma unroll
      for (int kt = 0; kt < 4; ++kt) sc[mt][kt] = (f32x4){0.f, 0.f, 0.f, 0.f};
#pragma unroll
    for (int dc = 0; dc < 4; ++dc) {
      bf16x8 bK[4];
#pragma unroll
      for (int kt = 0; kt < 4; ++kt)
        bK[kt] = *(const bf16x8*)&sK[(kt * 16 + l15) * 128 + (((dc * 4 + quad) ^ x7) << 3)];
#pragma unroll
      for (int mt = 0; mt < 2; ++mt)
#pragma unroll
        for (int kt = 0; kt < 4; ++kt)
          sc[mt][kt] = __builtin_amdgcn_mfma_f32_16x16x32_bf16(Qf[mt][dc], bK[kt], sc[mt][kt], 0, 0, 0);
    }
    if (k0 + 63 - HISTN > q0) {   // causal boundary inside this step
#pragma unroll
      for (int mt = 0; mt < 2; ++mt)
#pragma unroll
        for (int kt = 0; kt < 4; ++kt) {
          int kg = k0 + kt * 16 + l15;
#pragma unroll
          for (int reg = 0; reg < 4; ++reg)
            if (kg > q0 + mt * 16 + quad * 4 + reg + HISTN) sc[mt][kt][reg] = -INFINITY;
        }
    }
    // ---- exp + P -> per-wave LDS patch (A-layout rows) ----
#pragma unroll
    for (int mt = 0; mt < 2; ++mt)
#pragma unroll
      for (int reg = 0; reg < 4; ++reg)
#pragma unroll
        for (int kt = 0; kt < 4; ++kt) {
          float p = __expf(sc[mt][kt][reg]);
          sPw[(mt * 16 + quad * 4 + reg) * 72 + kt * 16 + l15] = f2bf(p);
        }
    // ---- PV (+ constant ones-frag accumulates l) ----
#pragma unroll
    for (int kc = 0; kc < 2; ++kc) {
      bf16x8 aP[2];
#pragma unroll
      for (int mt = 0; mt < 2; ++mt)
        aP[mt] = *(const bf16x8*)&sPw[(mt * 16 + l15) * 72 + kc * 32 + q8];
#pragma unroll
      for (int dt = 0; dt < 8; ++dt) {
        bf16x8 bV = *(const bf16x8*)&sV[(dt * 16 + l15) * 64 + (((kc * 4 + quad) ^ x7) << 3)];
#pragma unroll
        for (int mt = 0; mt < 2; ++mt)
          o[mt][dt] = __builtin_amdgcn_mfma_f32_16x16x32_bf16(aP[mt], bV, o[mt][dt], 0, 0, 0);
      }
#pragma unroll
      for (int mt = 0; mt < 2; ++mt)
        ol[mt] = __builtin_amdgcn_mfma_f32_16x16x32_bf16(aP[mt], onesf, ol[mt], 0, 0, 0);
    }
  }

  // ---- accumulate partials: device-scope fp32 atomics ----
  float* ob = oacc + ((size_t)h * QL + q0) * 132;
#pragma unroll
  for (int mt = 0; mt < 2; ++mt)
#pragma unroll
    for (int reg = 0; reg < 4; ++reg) {
      int r = mt * 16 + quad * 4 + reg;
#pragma unroll
      for (int dt = 0; dt < 8; ++dt)
        atomicAdd(&ob[(size_t)r * 132 + dt * 16 + l15], o[mt][dt][reg]);
      if (l15 == 0) atomicAdd(&ob[(size_t)r * 132 + 128], ol[mt][reg]);
    }
}

// ---------- attn_norm: divide by l, emit bf16 hi/lo -------------------------
__global__ __launch_bounds__(256) void attn_norm(const float* __restrict__ oacc,
    u16* __restrict__ OH, u16* __restrict__ OL) {
  int fi = blockIdx.x * 256 + threadIdx.x;    // 786432 float4s
  int d4 = fi & 31;
  int q  = (fi >> 5) & 2047;
  int h  = fi >> 16;
  const float* row = oacc + ((size_t)h * QL + q) * 132;
  float inv = 1.f / row[128];
  float4 v = *(const float4*)&row[d4 * 4];
  size_t ob = (size_t)q * HID + h * HD + d4 * 4;
  float vals[4] = {v.x, v.y, v.z, v.w};
#pragma unroll
  for (int j = 0; j < 4; ++j) {
    float val = vals[j] * inv;
    u16 hv = f2bf(val);
    OH[ob + j] = hv;
    OL[ob + j] = f2bf(val - bf2f(hv));
  }
}

extern "C" void kernel_launch(void* const* d_in, const int* in_sizes, int n_in,
                              void* d_out, int out_size, void* d_ws, size_t ws_size,
                              hipStream_t stream) {
  (void)in_sizes; (void)n_in; (void)out_size; (void)ws_size;
  const float* x      = (const float*)d_in[0];
  const float* Wq     = (const float*)d_in[1];
  const float* bq     = (const float*)d_in[2];
  const float* Wk     = (const float*)d_in[3];
  const float* bk     = (const float*)d_in[4];
  const float* Wv     = (const float*)d_in[5];
  const float* bv     = (const float*)d_in[6];
  const float* Wo     = (const float*)d_in[7];
  const float* k_hist = (const float*)d_in[8];
  const float* v_hist = (const float*)d_in[9];
  const float* fcos   = (const float*)d_in[10];
  const float* fsin   = (const float*)d_in[11];
  float* out = (float*)d_out;

  char* p = (char*)d_ws;
  float* qkv   = (float*)p;  p += (size_t)QL * NQKV * 4;            // 16.78 MB
  u16*   Qb    = (u16*)p;    p += (size_t)NH * QL * HD * 2;
  u16*   Kb    = (u16*)p;    p += (size_t)NKVH * KLEN * HD * 2;
  u16*   Vtb   = (u16*)p;    p += (size_t)NKVH * VTROWS * KLEN * 2;
  u16*   xh    = (u16*)p;    p += (size_t)QL * HID * 2;             // alias attnH
  u16*   xl    = (u16*)p;    p += (size_t)QL * HID * 2;             // alias attnL
  u16*   WqkvH = (u16*)p;    p += (size_t)NQKV * HID * 2;
  u16*   WqkvL = (u16*)p;    p += (size_t)NQKV * HID * 2;
  u16*   WoH   = (u16*)p;    p += (size_t)HID * HID * 2;
  u16*   WoL   = (u16*)p;    p += (size_t)HID * HID * 2;
  float* bcat  = (float*)p;  p += (size_t)NQKV * 4;                 // ~64 MB total
  u16* attnH = xh;  u16* attnL = xl;    // x dead after QKV gemm
  float* oacc = qkv;                    // qkv dead after post; 12x2048x132 f32

  prep<<<4424, 256, 0, stream>>>(x, Wq, Wk, Wv, Wo, bq, bk, bv,
                                 xh, xl, WqkvH, WqkvL, WoH, WoL, bcat);
  gemm3<<<dim3(32, 32), 64, 0, stream>>>(xh, xl, WqkvH, WqkvL, bcat, qkv, HID, NQKV);
  post<<<2308, 256, 0, stream>>>(qkv, k_hist, v_hist, fcos, fsin, Qb, Kb, Vtb);
  hipMemsetAsync(oacc, 0, (size_t)NH * QL * 132 * 4, stream);
  attn6<<<dim3(256, 2), 384, 0, stream>>>(Qb, Kb, Vtb, oacc);
  attn_norm<<<3072, 256, 0, stream>>>(oacc, attnH, attnL);
  gemm3<<<dim3(24, 32), 64, 0, stream>>>(attnH, attnL, WoH, WoL, nullptr, out, HID, HID);
}